// Round 12
// baseline (217.182 us; speedup 1.0000x reference)
//
#include <hip/hip_runtime.h>
#include <hip/hip_bf16.h>
#include <math.h>

#define TT 4096
#define DD 2048
#define MM 512
#define EE 8
#define YMAX 112

typedef __attribute__((ext_vector_type(8))) short short8;
typedef __attribute__((ext_vector_type(4))) float f32x4;

// raw barrier: inline asm with memory clobber = HW barrier + compiler fence,
// WITHOUT __syncthreads' implicit s_waitcnt vmcnt(0) drain.
#define BARRIER() asm volatile("s_barrier" ::: "memory")
// Drain this wave's LDS reads BEFORE signalling a barrier. The WAR guarantee
// ("barrier after compute => safe to DMA-overwrite the buffer") requires
// reads to be COMPLETE, not merely issued: the compiler attaches lgkmcnt
// waits to the MFMA uses, and register-only MFMAs (with their waits) can
// legally sink past the barrier asm -> pending ds_read samples the NEXT
// tile (rule #18 class). R3's text passed by scheduling luck; R5/R9/R11's
// codegen perturbations exposed it.
#define LDS_READS_DONE() asm volatile("s_waitcnt lgkmcnt(0)" ::: "memory")

__device__ __forceinline__ unsigned short f2bf(float f) {
  union { float f; unsigned u; } v; v.f = f;
  unsigned u = v.u;
  unsigned r = u + 0x7FFFu + ((u >> 16) & 1u);
  return (unsigned short)(r >> 16);
}

__device__ __forceinline__ float bf2f(unsigned short u) {
  union { unsigned u; float f; } v; v.u = ((unsigned)u) << 16;
  return v.f;
}

__device__ __forceinline__ int imin(int a, int b) { return a < b ? a : b; }

__device__ __forceinline__ void gld16(const void* g, void* l) {
  __builtin_amdgcn_global_load_lds(
      (const __attribute__((address_space(1))) void*)g,
      (__attribute__((address_space(3))) void*)l, 16, 0, 0);
}

// ---------------------------------------------------------------------------
// prep (byte-identical round 8/10):
// blocks [0, 27*64): weight convert+transpose, 1 tile/wave, 8x8/lane.
// blocks [27*64, +1024): router, per-block partials (no global atomics).
// ---------------------------------------------------------------------------
__global__ __launch_bounds__(256) void prep_kernel(
    const float* __restrict__ wi0, const float* __restrict__ wi1,
    const float* __restrict__ wo, const float* __restrict__ swi0,
    const float* __restrict__ swi1, const float* __restrict__ swo,
    unsigned short* __restrict__ wi0T, unsigned short* __restrict__ wi1T,
    unsigned short* __restrict__ woT, unsigned short* __restrict__ swi0T,
    unsigned short* __restrict__ swi1T, unsigned short* __restrict__ swoT,
    const float* __restrict__ x, const float* __restrict__ wr,
    const float* __restrict__ wg, unsigned short* __restrict__ xb,
    int* __restrict__ topk_i, float* __restrict__ topk_w,
    float* __restrict__ gate, int* __restrict__ cnt_part,
    float* __restrict__ proxy_part)
{
  __shared__ float s_proxy[EE];
  __shared__ int s_cnt[EE];
  int b = blockIdx.x;
  int tid = threadIdx.x;

  if (b < 27 * 64) {
    int slice = b >> 6, q = b & 63;
    const float* s; unsigned short* d;
    int R, C, tcb;
    if (slice < 8)       { s = wi0 + (size_t)slice * DD * MM;        d = wi0T + (size_t)slice * DD * MM;        R = DD; C = MM; tcb = 3; }
    else if (slice < 16) { s = wi1 + (size_t)(slice - 8) * DD * MM;  d = wi1T + (size_t)(slice - 8) * DD * MM;  R = DD; C = MM; tcb = 3; }
    else if (slice < 24) { s = wo + (size_t)(slice - 16) * MM * DD;  d = woT + (size_t)(slice - 16) * MM * DD;  R = MM; C = DD; tcb = 5; }
    else if (slice == 24){ s = swi0; d = swi0T; R = DD; C = MM; tcb = 3; }
    else if (slice == 25){ s = swi1; d = swi1T; R = DD; C = MM; tcb = 3; }
    else                 { s = swo;  d = swoT;  R = MM; C = DD; tcb = 5; }
    int ncmask = (1 << tcb) - 1;

    int wv = tid >> 6, lane = tid & 63;
    int t = q * 4 + wv;
    int c0 = (t & ncmask) * 64, r0 = (t >> tcb) * 64;
    int r8 = (lane >> 3) * 8;
    int c8 = (lane & 7) * 8;

    const float* sp = s + (size_t)(r0 + r8) * C + (c0 + c8);
    float4 v[8][2];
#pragma unroll
    for (int j = 0; j < 8; ++j) {
      v[j][0] = *(const float4*)&sp[(size_t)j * C];
      v[j][1] = *(const float4*)&sp[(size_t)j * C + 4];
    }
    __builtin_amdgcn_sched_barrier(0);
    unsigned short u[8][8];
#pragma unroll
    for (int j = 0; j < 8; ++j) {
      u[j][0] = f2bf(v[j][0].x); u[j][1] = f2bf(v[j][0].y);
      u[j][2] = f2bf(v[j][0].z); u[j][3] = f2bf(v[j][0].w);
      u[j][4] = f2bf(v[j][1].x); u[j][5] = f2bf(v[j][1].y);
      u[j][6] = f2bf(v[j][1].z); u[j][7] = f2bf(v[j][1].w);
    }
    unsigned short* dp = d + (size_t)(c0 + c8) * R + (r0 + r8);
#pragma unroll
    for (int c = 0; c < 8; ++c) {
      short8 o;
#pragma unroll
      for (int j = 0; j < 8; ++j) o[j] = (short)u[j][c];
      *(short8*)&dp[(size_t)c * R] = o;
    }
    return;
  }

  // ---- router part: per-block partials, no global atomics ----
  int rb = b - 27 * 64;
  if (tid < EE) { s_proxy[tid] = 0.f; s_cnt[tid] = 0; }
  __syncthreads();
  int wave = tid >> 6, lane = tid & 63;
  int t = rb * 4 + wave;
  const float* xr = x + (size_t)t * DD;
  unsigned short* xbr = xb + (size_t)t * DD;

  float xv[32], wgv[32];
#pragma unroll
  for (int i = 0; i < 32; ++i) xv[i] = xr[lane + i * 64];
#pragma unroll
  for (int i = 0; i < 32; ++i) wgv[i] = wg[lane + i * 64];
#pragma unroll
  for (int i = 0; i < 32; ++i) xbr[lane + i * 64] = f2bf(xv[i]);

  float p[EE];
#pragma unroll
  for (int e = 0; e < EE; ++e) p[e] = 0.f;
  float pg = 0.f;
  for (int i = 0; i < DD / 64; ++i) {
    int d = lane + i * 64;
    const float* w = wr + d * EE;
#pragma unroll
    for (int e = 0; e < EE; ++e) p[e] = fmaf(xv[i], w[e], p[e]);
    pg = fmaf(xv[i], wgv[i], pg);
  }
#pragma unroll
  for (int e = 0; e < EE; ++e) {
#pragma unroll
    for (int off = 32; off; off >>= 1) p[e] += __shfl_xor(p[e], off);
  }
#pragma unroll
  for (int off = 32; off; off >>= 1) pg += __shfl_xor(pg, off);

  if (lane == 0) {
    float mx = p[0];
#pragma unroll
    for (int e = 1; e < EE; ++e) mx = fmaxf(mx, p[e]);
    float pr[EE]; float s = 0.f;
#pragma unroll
    for (int e = 0; e < EE; ++e) { pr[e] = __expf(p[e] - mx); s += pr[e]; }
    float inv = 1.f / s;
#pragma unroll
    for (int e = 0; e < EE; ++e) pr[e] *= inv;
    int i0 = 0;
#pragma unroll
    for (int e = 1; e < EE; ++e) if (p[e] > p[i0]) i0 = e;
    int i1 = (i0 == 0) ? 1 : 0;
#pragma unroll
    for (int e = 0; e < EE; ++e) if (e != i0 && p[e] > p[i1]) i1 = e;
    float w0 = pr[i0], w1 = pr[i1], s2 = w0 + w1;
    topk_i[t * 2] = i0; topk_i[t * 2 + 1] = i1;
    topk_w[t * 2] = w0 / s2; topk_w[t * 2 + 1] = w1 / s2;
    gate[t] = 1.f / (1.f + __expf(-pg));
    atomicAdd(&s_cnt[i0], 1);
    atomicAdd(&s_cnt[i1], 1);
#pragma unroll
    for (int e = 0; e < EE; ++e) atomicAdd(&s_proxy[e], pr[e]);
  }
  __syncthreads();
  if (tid < EE) {
    cnt_part[rb * EE + tid] = s_cnt[tid];
    proxy_part[rb * EE + tid] = s_proxy[tid];
  }
}

// ---------------------------------------------------------------------------
// offsets_loss: reduce partials -> cnt/offs/loss + packed tile table
// (tinfo[ty] = (z<<8)|(row0>>7), 128-row tiles, z ascending; ntile = count).
// ---------------------------------------------------------------------------
__global__ __launch_bounds__(256) void offsets_loss_kernel(
    const int* __restrict__ cnt_part, const float* __restrict__ proxy_part,
    int* __restrict__ cnt, int* __restrict__ offs, float* __restrict__ out_loss,
    int* __restrict__ tinfo, int* __restrict__ ntile)
{
  __shared__ int sc[256];
  __shared__ float sp[256];
  int tid = threadIdx.x;
  int e = tid & 7, g = tid >> 3;
  int ci = 0; float pi = 0.f;
  for (int b = g; b < TT / 4; b += 32) {
    ci += cnt_part[b * EE + e];
    pi += proxy_part[b * EE + e];
  }
  sc[tid] = ci; sp[tid] = pi;
  __syncthreads();
  if (tid < EE) {
    int c = 0; float p = 0.f;
    for (int g2 = 0; g2 < 32; ++g2) { c += sc[g2 * 8 + tid]; p += sp[g2 * 8 + tid]; }
    cnt[tid] = c;
    sc[tid] = c; sp[tid] = p;
  }
  __syncthreads();
  if (tid == 0) {
    int acc = 0; float l = 0.f;
    int nt = 0;
    for (int e2 = 0; e2 < EE; ++e2) {
      offs[e2] = acc; acc += sc[e2];
      l += (float)sc[e2] * sp[e2];
      for (int r0 = 0; r0 < sc[e2]; r0 += 128) tinfo[nt++] = (e2 << 8) | (r0 >> 7);
    }
    for (int r0 = 0; r0 < TT; r0 += 128) tinfo[nt++] = (EE << 8) | (r0 >> 7);
    ntile[0] = nt;
    out_loss[0] = l * (0.01f * (float)EE) / ((float)TT * (float)TT);
  }
}

// ---------------------------------------------------------------------------
__global__ __launch_bounds__(256) void fill_kernel(
    const int* __restrict__ topk_i, const int* __restrict__ offs,
    int* __restrict__ fillc, int* __restrict__ btok, int* __restrict__ slotOf)
{
  __shared__ int lh[EE], gb[EE];
  int tid = threadIdx.x;
  int idx = blockIdx.x * 256 + tid;
  if (tid < EE) lh[tid] = 0;
  __syncthreads();
  int e = topk_i[idx];
  int r = atomicAdd(&lh[e], 1);
  __syncthreads();
  if (tid < EE) gb[tid] = atomicAdd(&fillc[tid], lh[tid]);
  __syncthreads();
  int p = offs[e] + gb[e] + r;
  btok[p] = idx >> 1;
  slotOf[idx] = p;
}

// ---------------------------------------------------------------------------
// GEMM1: BK=32, 32-KB LDS (4x 8KB) -> 4-5 blocks/CU. 64-B LDS rows;
// swizzle: source chunk (lane&3)^((lane>>2)&3), read chunk grp^(row&3).
// Hardened prologue (vmcnt(0), order-independent) AND LDS_READS_DONE()
// at the end of compute — reads complete before the barrier that allows
// the buffer to be DMA-overwritten (the R5/R9/R11 race).
// ---------------------------------------------------------------------------
__global__ __launch_bounds__(256) void gemm1_kernel(
    const unsigned short* __restrict__ xb,
    const unsigned short* __restrict__ wi0T, const unsigned short* __restrict__ wi1T,
    const unsigned short* __restrict__ swi0T, const unsigned short* __restrict__ swi1T,
    unsigned short* __restrict__ H, unsigned short* __restrict__ Hs,
    const int* __restrict__ btok, const int* __restrict__ cnt, const int* __restrict__ offs,
    const int* __restrict__ tinfo, const int* __restrict__ ntile)
{
  __shared__ __align__(16) unsigned short lA0[128 * 32];   // 8 KB
  __shared__ __align__(16) unsigned short lA1[128 * 32];   // 8 KB
  __shared__ __align__(16) unsigned short lB0[128 * 32];   // 8 KB (0-63 mat0, 64-127 mat1)
  __shared__ __align__(16) unsigned short lB1[128 * 32];   // 8 KB
  int ty = blockIdx.y;
  if (ty >= ntile[0]) return;
  int ti = tinfo[ty];
  int z = ti >> 8;
  int row0 = (ti & 255) << 7;
  const unsigned short *w0, *w1;
  const int* tok = nullptr;
  unsigned short* Ho;
  int n;
  if (z < EE) {
    n = cnt[z];
    int rb = offs[z];
    tok = btok + rb;
    w0 = wi0T + (size_t)z * (DD * MM);
    w1 = wi1T + (size_t)z * (DD * MM);
    Ho = H + (size_t)rb * MM;
  } else { n = TT; w0 = swi0T; w1 = swi1T; Ho = Hs; }
  if (row0 >= n) return;
  int m0 = blockIdx.x * 64;
  int tid = threadIdx.x, lane = tid & 63, wv = tid >> 6;

  int ch4 = (lane & 3) ^ ((lane >> 2) & 3);   // source logical chunk (16B units)

  const unsigned short* gA[2];
  const unsigned short* gB[2];
#pragma unroll
  for (int c = 0; c < 2; ++c) {
    int row = (c * 4 + wv) * 16 + (lane >> 2);        // 0..127
    int tr;
    if (tok) tr = tok[imin(row0 + row, n - 1)];
    else     tr = row0 + row;
    gA[c] = xb + (size_t)tr * DD + ch4 * 8;
    int mat = row >> 6, col = row & 63;
    const unsigned short* wsel = mat ? w1 : w0;
    gB[c] = wsel + (size_t)(m0 + col) * DD + ch4 * 8;
  }

  int rw = (wv & 1) * 64;          // wave row base
  int cg = (wv >> 1) * 32;         // wave per-mat col base
  int fr = lane & 15;
  int grp = lane >> 4;             // 0..3
  int lr4 = (lane >> 4) * 4, lc = lane & 15;

  f32x4 acc[4][4];
  f32x4 zf = {0.f, 0.f, 0.f, 0.f};
#pragma unroll
  for (int i = 0; i < 4; ++i)
#pragma unroll
    for (int c = 0; c < 4; ++c) acc[i][c] = zf;

  auto stage = [&](int kk, unsigned short* la, unsigned short* lb) {
#pragma unroll
    for (int c = 0; c < 2; ++c) gld16(gA[c] + kk, la + (c * 4 + wv) * 512);
#pragma unroll
    for (int c = 0; c < 2; ++c) gld16(gB[c] + kk, lb + (c * 4 + wv) * 512);
  };
  auto compute = [&](const unsigned short* la, const unsigned short* lb) {
    short8 af[4], bf[4];
#pragma unroll
    for (int i = 0; i < 4; ++i) {
      int row = rw + i * 16 + fr;
      af[i] = *(const short8*)&la[row * 32 + ((grp ^ (row & 3)) * 8)];
    }
#pragma unroll
    for (int c = 0; c < 4; ++c) {
      int rowb = (c >> 1) * 64 + cg + (c & 1) * 16 + fr;
      bf[c] = *(const short8*)&lb[rowb * 32 + ((grp ^ (rowb & 3)) * 8)];
    }
#pragma unroll
    for (int i = 0; i < 4; ++i)
#pragma unroll
      for (int c = 0; c < 4; ++c)
        acc[i][c] = __builtin_amdgcn_mfma_f32_16x16x32_bf16(af[i], bf[c], acc[i][c], 0, 0, 0);
    LDS_READS_DONE();              // reads complete before the next barrier
  };

  // prologue: tiles 0 and 1 staged; FULL drain (order-independent, safe).
  stage(0, lA0, lB0);
  stage(32, lA1, lB1);
  asm volatile("s_waitcnt vmcnt(0)" ::: "memory");
  BARRIER();

#pragma unroll 1
  for (int j = 0; j < DD / 64 - 1; ++j) {
    int k0 = j * 64;
    compute(lA0, lB0);                 // tile 2j
    BARRIER();                         // all waves DONE reading buf0
    stage(k0 + 64, lA0, lB0);          // issue tile 2j+2
    asm volatile("s_waitcnt vmcnt(4)" ::: "memory");  // tile 2j+1 landed
    BARRIER();
    compute(lA1, lB1);                 // tile 2j+1
    BARRIER();
    stage(k0 + 96, lA1, lB1);          // issue tile 2j+3
    asm volatile("s_waitcnt vmcnt(4)" ::: "memory");  // tile 2j+2 landed
    BARRIER();
  }
  // epilogue: tiles NT-2 (buf0, already waited) and NT-1 (buf1)
  compute(lA0, lB0);
  asm volatile("s_waitcnt vmcnt(0)" ::: "memory");
  BARRIER();
  compute(lA1, lB1);

#pragma unroll
  for (int i = 0; i < 4; ++i) {
#pragma unroll
    for (int c = 0; c < 2; ++c) {
#pragma unroll
      for (int rg = 0; rg < 4; ++rg) {
        int row = row0 + rw + i * 16 + lr4 + rg;
        if (row < n) {
          float a0 = acc[i][c][rg];
          float a1 = acc[i][c + 2][rg];
          float h = a0 / (1.f + __expf(-a0)) * a1;
          Ho[(size_t)row * MM + m0 + cg + c * 16 + lc] = f2bf(h);
        }
      }
    }
  }
}

// ---------------------------------------------------------------------------
// GEMM2: Y = H @ woT. Same BK=32 / 32-KB / hardened transform
// (K = MM = 512, 16 tiles). Tile 128 rows x 128 d-cols, tile-table packed.
// ---------------------------------------------------------------------------
__global__ __launch_bounds__(256) void gemm2_kernel(
    const unsigned short* __restrict__ H, const unsigned short* __restrict__ Hs,
    const unsigned short* __restrict__ woT, const unsigned short* __restrict__ swoT,
    unsigned short* __restrict__ Yr, unsigned short* __restrict__ Ys,
    const int* __restrict__ cnt, const int* __restrict__ offs,
    const int* __restrict__ tinfo, const int* __restrict__ ntile)
{
  __shared__ __align__(16) unsigned short lA0[128 * 32];
  __shared__ __align__(16) unsigned short lA1[128 * 32];
  __shared__ __align__(16) unsigned short lB0[128 * 32];   // rows = out cols
  __shared__ __align__(16) unsigned short lB1[128 * 32];
  int ty = blockIdx.y;
  if (ty >= ntile[0]) return;
  int ti = tinfo[ty];
  int z = ti >> 8;
  int row0 = (ti & 255) << 7;
  int n, rb;
  const unsigned short *Hb, *wb;
  unsigned short* Yd;
  if (z < EE) { n = cnt[z]; rb = offs[z]; Hb = H + (size_t)rb * MM; wb = woT + (size_t)z * (DD * MM); Yd = Yr + (size_t)rb * DD; }
  else        { n = TT; rb = 0; Hb = Hs; wb = swoT; Yd = Ys; }
  if (row0 >= n) return;
  int d0 = blockIdx.x * 128;
  int tid = threadIdx.x, lane = tid & 63, wv = tid >> 6;

  int ch4 = (lane & 3) ^ ((lane >> 2) & 3);

  const unsigned short* gA[2];
  const unsigned short* gB[2];
#pragma unroll
  for (int c = 0; c < 2; ++c) {
    int row = (c * 4 + wv) * 16 + (lane >> 2);
    int sr = imin(row0 + row, n - 1);
    gA[c] = Hb + (size_t)sr * MM + ch4 * 8;
    gB[c] = wb + (size_t)(d0 + row) * MM + ch4 * 8;
  }

  int rw = (wv & 1) * 64;
  int cw = (wv >> 1) * 64;
  int fr = lane & 15;
  int grp = lane >> 4;
  int lr4 = (lane >> 4) * 4, lc = lane & 15;

  f32x4 acc[4][4];
  f32x4 zf = {0.f, 0.f, 0.f, 0.f};
#pragma unroll
  for (int i = 0; i < 4; ++i)
#pragma unroll
    for (int c = 0; c < 4; ++c) acc[i][c] = zf;

  auto stage = [&](int kk, unsigned short* la, unsigned short* lb) {
#pragma unroll
    for (int c = 0; c < 2; ++c) gld16(gA[c] + kk, la + (c * 4 + wv) * 512);
#pragma unroll
    for (int c = 0; c < 2; ++c) gld16(gB[c] + kk, lb + (c * 4 + wv) * 512);
  };
  auto compute = [&](const unsigned short* la, const unsigned short* lb) {
    short8 af[4], bf[4];
#pragma unroll
    for (int i = 0; i < 4; ++i) {
      int row = rw + i * 16 + fr;
      af[i] = *(const short8*)&la[row * 32 + ((grp ^ (row & 3)) * 8)];
    }
#pragma unroll
    for (int c = 0; c < 4; ++c) {
      int rowb = cw + c * 16 + fr;
      bf[c] = *(const short8*)&lb[rowb * 32 + ((grp ^ (rowb & 3)) * 8)];
    }
#pragma unroll
    for (int i = 0; i < 4; ++i)
#pragma unroll
      for (int c = 0; c < 4; ++c)
        acc[i][c] = __builtin_amdgcn_mfma_f32_16x16x32_bf16(af[i], bf[c], acc[i][c], 0, 0, 0);
    LDS_READS_DONE();
  };

  // prologue: full drain (order-independent, safe)
  stage(0, lA0, lB0);
  stage(32, lA1, lB1);
  asm volatile("s_waitcnt vmcnt(0)" ::: "memory");
  BARRIER();

#pragma unroll 1
  for (int j = 0; j < MM / 64 - 1; ++j) {
    int k0 = j * 64;
    compute(lA0, lB0);
    BARRIER();
    stage(k0 + 64, lA0, lB0);
    asm volatile("s_waitcnt vmcnt(4)" ::: "memory");
    BARRIER();
    compute(lA1, lB1);
    BARRIER();
    stage(k0 + 96, lA1, lB1);
    asm volatile("s_waitcnt vmcnt(4)" ::: "memory");
    BARRIER();
  }
  compute(lA0, lB0);
  asm volatile("s_waitcnt vmcnt(0)" ::: "memory");
  BARRIER();
  compute(lA1, lB1);

#pragma unroll
  for (int i = 0; i < 4; ++i) {
#pragma unroll
    for (int c = 0; c < 4; ++c) {
#pragma unroll
      for (int rg = 0; rg < 4; ++rg) {
        int row = row0 + rw + i * 16 + lr4 + rg;
        if (row < n)
          Yd[(size_t)row * DD + d0 + cw + c * 16 + lc] = f2bf(acc[i][c][rg]);
      }
    }
  }
}

// ---------------------------------------------------------------------------
// Combine: out[t][d] = gate[t]*Ys[t][d] + w0*Yr[p0][d] + w1*Yr[p1][d]
// ---------------------------------------------------------------------------
__global__ __launch_bounds__(256) void combine_kernel(
    const unsigned short* __restrict__ Yr, const unsigned short* __restrict__ Ys,
    const int* __restrict__ slotOf, const float* __restrict__ topk_w,
    const float* __restrict__ gate, float* __restrict__ out)
{
  int t = blockIdx.x;
  int d0 = threadIdx.x * 8;
  int p0 = slotOf[t * 2], p1 = slotOf[t * 2 + 1];
  float w0 = topk_w[t * 2], w1 = topk_w[t * 2 + 1], g = gate[t];
  short8 a = *(const short8*)&Yr[(size_t)p0 * DD + d0];
  short8 b = *(const short8*)&Yr[(size_t)p1 * DD + d0];
  short8 s = *(const short8*)&Ys[(size_t)t * DD + d0];
  float r[8];
#pragma unroll
  for (int j = 0; j < 8; ++j)
    r[j] = w0 * bf2f((unsigned short)a[j]) + w1 * bf2f((unsigned short)b[j])
         + g * bf2f((unsigned short)s[j]);
  float4 o0 = {r[0], r[1], r[2], r[3]};
  float4 o1 = {r[4], r[5], r[6], r[7]};
  float* op = out + (size_t)t * DD + d0;
  *(float4*)op = o0;
  *(float4*)(op + 4) = o1;
}

// ---------------------------------------------------------------------------
extern "C" void kernel_launch(void* const* d_in, const int* in_sizes, int n_in,
                              void* d_out, int out_size, void* d_ws, size_t ws_size,
                              hipStream_t stream) {
  const float* x    = (const float*)d_in[0];
  const float* wr   = (const float*)d_in[1];
  const float* wi0  = (const float*)d_in[2];
  const float* wi1  = (const float*)d_in[3];
  const float* wo   = (const float*)d_in[4];
  const float* swi0 = (const float*)d_in[5];
  const float* swi1 = (const float*)d_in[6];
  const float* swo  = (const float*)d_in[7];
  const float* wg   = (const float*)d_in[8];
  float* out = (float*)d_out;

  char* ws = (char*)d_ws;
  int*   cnt    = (int*)(ws + 0);
  int*   fillc  = (int*)(ws + 64);
  int*   offs   = (int*)(ws + 128);
  int*   ntile  = (int*)(ws + 192);
  int*   tinfo  = (int*)(ws + 256);                        // 112 ints
  int*   topk_i = (int*)(ws + 1024);
  float* topk_w = (float*)(ws + 33792);
  int*   btok   = (int*)(ws + 66560);
  float* gate   = (float*)(ws + 132096);
  int*   slotOf = (int*)(ws + 148480);
  int*   cnt_part   = (int*)(ws + 262144);                 // 32 KB
  float* proxy_part = (float*)(ws + 294912);               // 32 KB
  unsigned short* xb    = (unsigned short*)(ws + 1048576);   // 16 MB; reused as Ys
  unsigned short* H     = (unsigned short*)(ws + 17825792);  // 8 MB
  unsigned short* Hs    = (unsigned short*)(ws + 26214400);  // 4 MB
  unsigned short* wi0T  = (unsigned short*)(ws + 30408704);  // 16 MB; reused as Yr (+wi1T)
  unsigned short* wi1T  = (unsigned short*)(ws + 47185920);  // 16 MB
  unsigned short* woT   = (unsigned short*)(ws + 63963136);  // 16 MB
  unsigned short* swi0T = (unsigned short*)(ws + 80740352);  // 2 MB
  unsigned short* swi1T = (unsigned short*)(ws + 82837504);  // 2 MB
  unsigned short* swoT  = (unsigned short*)(ws + 84934656);  // 2 MB
  unsigned short* Ys = xb;
  unsigned short* Yr = wi0T;

  hipMemsetAsync(ws, 0, 256, stream);

  prep_kernel<<<27 * 64 + TT / 4, 256, 0, stream>>>(
      wi0, wi1, wo, swi0, swi1, swo, wi0T, wi1T, woT, swi0T, swi1T, swoT,
      x, wr, wg, xb, topk_i, topk_w, gate, cnt_part, proxy_part);
  offsets_loss_kernel<<<1, 256, 0, stream>>>(
      cnt_part, proxy_part, cnt, offs, out + (size_t)TT * DD, tinfo, ntile);
  fill_kernel<<<(TT * 2) / 256, 256, 0, stream>>>(topk_i, offs, fillc, btok, slotOf);

  gemm1_kernel<<<dim3(MM / 64, YMAX, 1), 256, 0, stream>>>(
      xb, wi0T, wi1T, swi0T, swi1T, H, Hs, btok, cnt, offs, tinfo, ntile);
  gemm2_kernel<<<dim3(DD / 128, YMAX, 1), 256, 0, stream>>>(
      H, Hs, woT, swoT, Yr, Ys, cnt, offs, tinfo, ntile);
  combine_kernel<<<TT, 256, 0, stream>>>(Yr, Ys, slotOf, topk_w, gate, out);
}

// Round 13
// 196.905 us; speedup vs baseline: 1.1030x; 1.1030x over previous
//
#include <hip/hip_runtime.h>
#include <hip/hip_bf16.h>
#include <math.h>

#define TT 4096
#define DD 2048
#define MM 512
#define EE 8

typedef __attribute__((ext_vector_type(8))) short short8;
typedef __attribute__((ext_vector_type(4))) float f32x4;

// raw barrier: inline asm with memory clobber = HW barrier + compiler fence,
// WITHOUT __syncthreads' implicit s_waitcnt vmcnt(0) drain.
#define BARRIER() asm volatile("s_barrier" ::: "memory")
// Drain this wave's LDS reads BEFORE signalling a barrier. The WAR guarantee
// ("barrier after compute => safe to DMA-overwrite the buffer") requires
// reads COMPLETE, not merely issued: hipcc attaches lgkmcnt waits to the
// MFMA uses, and register-only MFMAs (with their waits) can sink past the
// barrier asm (memory clobber doesn't order them) -> a pending ds_read
// samples the NEXT tile. Confirmed in R12: R9/R11 failed without this,
// passed with it. R3/R8's schedule was lucky; this makes it structural.
#define LDS_READS_DONE() asm volatile("s_waitcnt lgkmcnt(0)" ::: "memory")

__device__ __forceinline__ unsigned short f2bf(float f) {
  union { float f; unsigned u; } v; v.f = f;
  unsigned u = v.u;
  unsigned r = u + 0x7FFFu + ((u >> 16) & 1u);
  return (unsigned short)(r >> 16);
}

__device__ __forceinline__ float bf2f(unsigned short u) {
  union { unsigned u; float f; } v; v.u = ((unsigned)u) << 16;
  return v.f;
}

__device__ __forceinline__ int imin(int a, int b) { return a < b ? a : b; }

__device__ __forceinline__ void gld16(const void* g, void* l) {
  __builtin_amdgcn_global_load_lds(
      (const __attribute__((address_space(1))) void*)g,
      (__attribute__((address_space(3))) void*)l, 16, 0, 0);
}

// ---------------------------------------------------------------------------
// prep (round-8 text):
// blocks [0, 27*64): weight convert+transpose, 1 tile/wave, 8x8/lane.
// blocks [27*64, +1024): router, per-block partials (no global atomics).
// ---------------------------------------------------------------------------
__global__ __launch_bounds__(256) void prep_kernel(
    const float* __restrict__ wi0, const float* __restrict__ wi1,
    const float* __restrict__ wo, const float* __restrict__ swi0,
    const float* __restrict__ swi1, const float* __restrict__ swo,
    unsigned short* __restrict__ wi0T, unsigned short* __restrict__ wi1T,
    unsigned short* __restrict__ woT, unsigned short* __restrict__ swi0T,
    unsigned short* __restrict__ swi1T, unsigned short* __restrict__ swoT,
    const float* __restrict__ x, const float* __restrict__ wr,
    const float* __restrict__ wg, unsigned short* __restrict__ xb,
    int* __restrict__ topk_i, float* __restrict__ topk_w,
    float* __restrict__ gate, int* __restrict__ cnt_part,
    float* __restrict__ proxy_part)
{
  __shared__ float s_proxy[EE];
  __shared__ int s_cnt[EE];
  int b = blockIdx.x;
  int tid = threadIdx.x;

  if (b < 27 * 64) {
    int slice = b >> 6, q = b & 63;
    const float* s; unsigned short* d;
    int R, C, tcb;
    if (slice < 8)       { s = wi0 + (size_t)slice * DD * MM;        d = wi0T + (size_t)slice * DD * MM;        R = DD; C = MM; tcb = 3; }
    else if (slice < 16) { s = wi1 + (size_t)(slice - 8) * DD * MM;  d = wi1T + (size_t)(slice - 8) * DD * MM;  R = DD; C = MM; tcb = 3; }
    else if (slice < 24) { s = wo + (size_t)(slice - 16) * MM * DD;  d = woT + (size_t)(slice - 16) * MM * DD;  R = MM; C = DD; tcb = 5; }
    else if (slice == 24){ s = swi0; d = swi0T; R = DD; C = MM; tcb = 3; }
    else if (slice == 25){ s = swi1; d = swi1T; R = DD; C = MM; tcb = 3; }
    else                 { s = swo;  d = swoT;  R = MM; C = DD; tcb = 5; }
    int ncmask = (1 << tcb) - 1;

    int wv = tid >> 6, lane = tid & 63;
    int t = q * 4 + wv;
    int c0 = (t & ncmask) * 64, r0 = (t >> tcb) * 64;
    int r8 = (lane >> 3) * 8;
    int c8 = (lane & 7) * 8;

    const float* sp = s + (size_t)(r0 + r8) * C + (c0 + c8);
    float4 v[8][2];
#pragma unroll
    for (int j = 0; j < 8; ++j) {
      v[j][0] = *(const float4*)&sp[(size_t)j * C];
      v[j][1] = *(const float4*)&sp[(size_t)j * C + 4];
    }
    __builtin_amdgcn_sched_barrier(0);
    unsigned short u[8][8];
#pragma unroll
    for (int j = 0; j < 8; ++j) {
      u[j][0] = f2bf(v[j][0].x); u[j][1] = f2bf(v[j][0].y);
      u[j][2] = f2bf(v[j][0].z); u[j][3] = f2bf(v[j][0].w);
      u[j][4] = f2bf(v[j][1].x); u[j][5] = f2bf(v[j][1].y);
      u[j][6] = f2bf(v[j][1].z); u[j][7] = f2bf(v[j][1].w);
    }
    unsigned short* dp = d + (size_t)(c0 + c8) * R + (r0 + r8);
#pragma unroll
    for (int c = 0; c < 8; ++c) {
      short8 o;
#pragma unroll
      for (int j = 0; j < 8; ++j) o[j] = (short)u[j][c];
      *(short8*)&dp[(size_t)c * R] = o;
    }
    return;
  }

  // ---- router part: per-block partials, no global atomics ----
  int rb = b - 27 * 64;
  if (tid < EE) { s_proxy[tid] = 0.f; s_cnt[tid] = 0; }
  __syncthreads();
  int wave = tid >> 6, lane = tid & 63;
  int t = rb * 4 + wave;
  const float* xr = x + (size_t)t * DD;
  unsigned short* xbr = xb + (size_t)t * DD;

  float xv[32], wgv[32];
#pragma unroll
  for (int i = 0; i < 32; ++i) xv[i] = xr[lane + i * 64];
#pragma unroll
  for (int i = 0; i < 32; ++i) wgv[i] = wg[lane + i * 64];
#pragma unroll
  for (int i = 0; i < 32; ++i) xbr[lane + i * 64] = f2bf(xv[i]);

  float p[EE];
#pragma unroll
  for (int e = 0; e < EE; ++e) p[e] = 0.f;
  float pg = 0.f;
  for (int i = 0; i < DD / 64; ++i) {
    int d = lane + i * 64;
    const float* w = wr + d * EE;
#pragma unroll
    for (int e = 0; e < EE; ++e) p[e] = fmaf(xv[i], w[e], p[e]);
    pg = fmaf(xv[i], wgv[i], pg);
  }
#pragma unroll
  for (int e = 0; e < EE; ++e) {
#pragma unroll
    for (int off = 32; off; off >>= 1) p[e] += __shfl_xor(p[e], off);
  }
#pragma unroll
  for (int off = 32; off; off >>= 1) pg += __shfl_xor(pg, off);

  if (lane == 0) {
    float mx = p[0];
#pragma unroll
    for (int e = 1; e < EE; ++e) mx = fmaxf(mx, p[e]);
    float pr[EE]; float s = 0.f;
#pragma unroll
    for (int e = 0; e < EE; ++e) { pr[e] = __expf(p[e] - mx); s += pr[e]; }
    float inv = 1.f / s;
#pragma unroll
    for (int e = 0; e < EE; ++e) pr[e] *= inv;
    int i0 = 0;
#pragma unroll
    for (int e = 1; e < EE; ++e) if (p[e] > p[i0]) i0 = e;
    int i1 = (i0 == 0) ? 1 : 0;
#pragma unroll
    for (int e = 0; e < EE; ++e) if (e != i0 && p[e] > p[i1]) i1 = e;
    float w0 = pr[i0], w1 = pr[i1], s2 = w0 + w1;
    topk_i[t * 2] = i0; topk_i[t * 2 + 1] = i1;
    topk_w[t * 2] = w0 / s2; topk_w[t * 2 + 1] = w1 / s2;
    gate[t] = 1.f / (1.f + __expf(-pg));
    atomicAdd(&s_cnt[i0], 1);
    atomicAdd(&s_cnt[i1], 1);
#pragma unroll
    for (int e = 0; e < EE; ++e) atomicAdd(&s_proxy[e], pr[e]);
  }
  __syncthreads();
  if (tid < EE) {
    cnt_part[rb * EE + tid] = s_cnt[tid];
    proxy_part[rb * EE + tid] = s_proxy[tid];
  }
}

// ---------------------------------------------------------------------------
// offsets_loss: reduce 1024 per-block partials -> cnt/offs/loss. 1 block,
// 256 threads (32 reduction groups x 8 experts), 64KB L2-resident traffic.
// ---------------------------------------------------------------------------
__global__ __launch_bounds__(256) void offsets_loss_kernel(
    const int* __restrict__ cnt_part, const float* __restrict__ proxy_part,
    int* __restrict__ cnt, int* __restrict__ offs, float* __restrict__ out_loss)
{
  __shared__ int sc[256];
  __shared__ float sp[256];
  int tid = threadIdx.x;
  int e = tid & 7, g = tid >> 3;       // 32 groups per expert
  int ci = 0; float pi = 0.f;
  for (int b = g; b < TT / 4; b += 32) {
    ci += cnt_part[b * EE + e];
    pi += proxy_part[b * EE + e];
  }
  sc[tid] = ci; sp[tid] = pi;
  __syncthreads();
  if (tid < EE) {
    int c = 0; float p = 0.f;
    for (int g2 = 0; g2 < 32; ++g2) { c += sc[g2 * 8 + tid]; p += sp[g2 * 8 + tid]; }
    cnt[tid] = c;
    sc[tid] = c; sp[tid] = p;          // same-wave lockstep: loop reads done
  }
  __syncthreads();
  if (tid == 0) {
    int acc = 0; float l = 0.f;
    for (int e2 = 0; e2 < EE; ++e2) {
      offs[e2] = acc; acc += sc[e2];
      l += (float)sc[e2] * sp[e2];
    }
    out_loss[0] = l * (0.01f * (float)EE) / ((float)TT * (float)TT);
  }
}

// ---------------------------------------------------------------------------
// fill: per-block LDS histogram; ONE global atomic per expert per block
// (256 total). Intra-block rank from the LDS atomic's return value.
// ---------------------------------------------------------------------------
__global__ __launch_bounds__(256) void fill_kernel(
    const int* __restrict__ topk_i, const int* __restrict__ offs,
    int* __restrict__ fillc, int* __restrict__ btok, int* __restrict__ slotOf)
{
  __shared__ int lh[EE], gb[EE];
  int tid = threadIdx.x;
  int idx = blockIdx.x * 256 + tid;    // grid = 8192/256 exact
  if (tid < EE) lh[tid] = 0;
  __syncthreads();
  int e = topk_i[idx];
  int r = atomicAdd(&lh[e], 1);        // intra-block rank
  __syncthreads();
  if (tid < EE) gb[tid] = atomicAdd(&fillc[tid], lh[tid]);
  __syncthreads();
  int p = offs[e] + gb[e] + r;
  btok[p] = idx >> 1;
  slotOf[idx] = p;
}

// ---------------------------------------------------------------------------
// GEMM1: H[row][m] = silu(x@wi0)*(x@wi1). Round-8 structure (the session
// best: 83us, 0 bank conflicts, MfmaUtil 26% = its LDS-read-BW ceiling):
// tile 128 rows x (64 m-cols x 2 mats), BK=64; counted-vmcnt double-buffer;
// raw s_barrier; + LDS_READS_DONE() closing the R12-confirmed WAR race.
// ---------------------------------------------------------------------------
__global__ __launch_bounds__(256) void gemm1_kernel(
    const unsigned short* __restrict__ xb,
    const unsigned short* __restrict__ wi0T, const unsigned short* __restrict__ wi1T,
    const unsigned short* __restrict__ swi0T, const unsigned short* __restrict__ swi1T,
    unsigned short* __restrict__ H, unsigned short* __restrict__ Hs,
    const int* __restrict__ btok, const int* __restrict__ cnt, const int* __restrict__ offs)
{
  __shared__ __align__(16) unsigned short lA0[128 * 64];   // 16 KB
  __shared__ __align__(16) unsigned short lA1[128 * 64];   // 16 KB
  __shared__ __align__(16) unsigned short lB0[128 * 64];   // 16 KB (0-63 mat0, 64-127 mat1)
  __shared__ __align__(16) unsigned short lB1[128 * 64];   // 16 KB
  int z = blockIdx.z;
  const unsigned short *w0, *w1;
  const int* tok = nullptr;
  unsigned short* Ho;
  int n;
  if (z < EE) {
    n = cnt[z];
    int rb = offs[z];
    tok = btok + rb;
    w0 = wi0T + (size_t)z * (DD * MM);
    w1 = wi1T + (size_t)z * (DD * MM);
    Ho = H + (size_t)rb * MM;
  } else { n = TT; w0 = swi0T; w1 = swi1T; Ho = Hs; }
  int row0 = blockIdx.y * 128;
  if (row0 >= n) return;
  int m0 = blockIdx.x * 64;
  int tid = threadIdx.x, lane = tid & 63, wv = tid >> 6;

  int lsub = lane >> 3;            // 0..7 = row&7
  int chl = (lane & 7) ^ lsub;     // logical chunk for this lane's cell

  const unsigned short* gA[4];
  const unsigned short* gB[4];
#pragma unroll
  for (int c = 0; c < 4; ++c) {
    int row = c * 32 + wv * 8 + lsub;                 // 0..127
    int tr;
    if (tok) tr = tok[imin(row0 + row, n - 1)];
    else     tr = row0 + row;
    gA[c] = xb + (size_t)tr * DD + chl * 8;
    int mat = row >> 6, col = row & 63;
    const unsigned short* wsel = mat ? w1 : w0;
    gB[c] = wsel + (size_t)(m0 + col) * DD + chl * 8;
  }

  int rw = (wv & 1) * 64;          // wave row base
  int cg = (wv >> 1) * 32;         // wave per-mat col base
  int fr = lane & 15;
  int grp = lane >> 4;             // 0..3
  int lr4 = (lane >> 4) * 4, lc = lane & 15;

  f32x4 acc[4][4];
  f32x4 zf = {0.f, 0.f, 0.f, 0.f};
#pragma unroll
  for (int i = 0; i < 4; ++i)
#pragma unroll
    for (int c = 0; c < 4; ++c) acc[i][c] = zf;

  auto stage = [&](int kk, unsigned short* la, unsigned short* lb) {
#pragma unroll
    for (int c = 0; c < 4; ++c) gld16(gA[c] + kk, la + c * 2048 + wv * 512);
#pragma unroll
    for (int c = 0; c < 4; ++c) gld16(gB[c] + kk, lb + c * 2048 + wv * 512);
  };
  auto compute = [&](const unsigned short* la, const unsigned short* lb) {
#pragma unroll
    for (int s = 0; s < 2; ++s) {
      int cq = s * 4 + grp;        // logical chunk for this frag read
      short8 af[4], bf[4];
#pragma unroll
      for (int i = 0; i < 4; ++i) {
        int row = rw + i * 16 + fr;
        af[i] = *(const short8*)&la[row * 64 + ((cq ^ (row & 7)) * 8)];
      }
#pragma unroll
      for (int c = 0; c < 4; ++c) {
        int rowb = (c >> 1) * 64 + cg + (c & 1) * 16 + fr;
        bf[c] = *(const short8*)&lb[rowb * 64 + ((cq ^ (rowb & 7)) * 8)];
      }
#pragma unroll
      for (int i = 0; i < 4; ++i)
#pragma unroll
        for (int c = 0; c < 4; ++c)
          acc[i][c] = __builtin_amdgcn_mfma_f32_16x16x32_bf16(af[i], bf[c], acc[i][c], 0, 0, 0);
    }
    LDS_READS_DONE();              // reads complete before the next barrier
  };

  // prologue: tiles 0 and 1 staged; full drain (order-independent, safe)
  stage(0, lA0, lB0);
  stage(64, lA1, lB1);
  asm volatile("s_waitcnt vmcnt(0)" ::: "memory");
  BARRIER();

#pragma unroll 1
  for (int j = 0; j < DD / 128 - 1; ++j) {
    int k0 = j * 128;
    compute(lA0, lB0);                 // tile 2j
    BARRIER();                         // all waves DONE reading buf0
    stage(k0 + 128, lA0, lB0);         // issue tile 2j+2
    asm volatile("s_waitcnt vmcnt(8)" ::: "memory");  // tile 2j+1 landed
    BARRIER();
    compute(lA1, lB1);                 // tile 2j+1
    BARRIER();
    stage(k0 + 192, lA1, lB1);         // issue tile 2j+3
    asm volatile("s_waitcnt vmcnt(8)" ::: "memory");  // tile 2j+2 landed
    BARRIER();
  }
  // epilogue: tiles NT-2 (buf0, already waited) and NT-1 (buf1)
  compute(lA0, lB0);
  asm volatile("s_waitcnt vmcnt(0)" ::: "memory");
  BARRIER();
  compute(lA1, lB1);

#pragma unroll
  for (int i = 0; i < 4; ++i) {
#pragma unroll
    for (int c = 0; c < 2; ++c) {
#pragma unroll
      for (int rg = 0; rg < 4; ++rg) {
        int row = row0 + rw + i * 16 + lr4 + rg;
        if (row < n) {
          float a0 = acc[i][c][rg];
          float a1 = acc[i][c + 2][rg];
          float h = a0 / (1.f + __expf(-a0)) * a1;
          Ho[(size_t)row * MM + m0 + cg + c * 16 + lc] = f2bf(h);
        }
      }
    }
  }
}

// ---------------------------------------------------------------------------
// GEMM2: Y = H @ woT. Round-8 structure + LDS_READS_DONE(). Tile 128 rows
// x 128 d-cols, BK=64; counted-vmcnt double-buffer; raw s_barrier.
// ---------------------------------------------------------------------------
__global__ __launch_bounds__(256) void gemm2_kernel(
    const unsigned short* __restrict__ H, const unsigned short* __restrict__ Hs,
    const unsigned short* __restrict__ woT, const unsigned short* __restrict__ swoT,
    unsigned short* __restrict__ Yr, unsigned short* __restrict__ Ys,
    const int* __restrict__ cnt, const int* __restrict__ offs)
{
  __shared__ __align__(16) unsigned short lA0[128 * 64];
  __shared__ __align__(16) unsigned short lA1[128 * 64];
  __shared__ __align__(16) unsigned short lB0[128 * 64];   // rows = out cols
  __shared__ __align__(16) unsigned short lB1[128 * 64];
  int z = blockIdx.z;
  int n, rb;
  const unsigned short *Hb, *wb;
  unsigned short* Yd;
  if (z < EE) { n = cnt[z]; rb = offs[z]; Hb = H + (size_t)rb * MM; wb = woT + (size_t)z * (DD * MM); Yd = Yr + (size_t)rb * DD; }
  else        { n = TT; rb = 0; Hb = Hs; wb = swoT; Yd = Ys; }
  int row0 = blockIdx.y * 128;
  if (row0 >= n) return;
  int d0 = blockIdx.x * 128;
  int tid = threadIdx.x, lane = tid & 63, wv = tid >> 6;

  int lsub = lane >> 3;
  int chl = (lane & 7) ^ lsub;

  const unsigned short* gA[4];
  const unsigned short* gB[4];
#pragma unroll
  for (int c = 0; c < 4; ++c) {
    int row = c * 32 + wv * 8 + lsub;
    int sr = imin(row0 + row, n - 1);
    gA[c] = Hb + (size_t)sr * MM + chl * 8;
    gB[c] = wb + (size_t)(d0 + row) * MM + chl * 8;
  }

  int rw = (wv & 1) * 64;
  int cw = (wv >> 1) * 64;
  int fr = lane & 15;
  int grp = lane >> 4;
  int lr4 = (lane >> 4) * 4, lc = lane & 15;

  f32x4 acc[4][4];
  f32x4 zf = {0.f, 0.f, 0.f, 0.f};
#pragma unroll
  for (int i = 0; i < 4; ++i)
#pragma unroll
    for (int c = 0; c < 4; ++c) acc[i][c] = zf;

  auto stage = [&](int kk, unsigned short* la, unsigned short* lb) {
#pragma unroll
    for (int c = 0; c < 4; ++c) gld16(gA[c] + kk, la + c * 2048 + wv * 512);
#pragma unroll
    for (int c = 0; c < 4; ++c) gld16(gB[c] + kk, lb + c * 2048 + wv * 512);
  };
  auto compute = [&](const unsigned short* la, const unsigned short* lb) {
#pragma unroll
    for (int s = 0; s < 2; ++s) {
      int cq = s * 4 + grp;
      short8 af[4], bf[4];
#pragma unroll
      for (int i = 0; i < 4; ++i) {
        int row = rw + i * 16 + fr;
        af[i] = *(const short8*)&la[row * 64 + ((cq ^ (row & 7)) * 8)];
      }
#pragma unroll
      for (int c = 0; c < 4; ++c) {
        int rowb = cw + c * 16 + fr;
        bf[c] = *(const short8*)&lb[rowb * 64 + ((cq ^ (rowb & 7)) * 8)];
      }
#pragma unroll
      for (int i = 0; i < 4; ++i)
#pragma unroll
        for (int c = 0; c < 4; ++c)
          acc[i][c] = __builtin_amdgcn_mfma_f32_16x16x32_bf16(af[i], bf[c], acc[i][c], 0, 0, 0);
    }
    LDS_READS_DONE();
  };

  // prologue: full drain (order-independent, safe)
  stage(0, lA0, lB0);
  stage(64, lA1, lB1);
  asm volatile("s_waitcnt vmcnt(0)" ::: "memory");
  BARRIER();

#pragma unroll 1
  for (int j = 0; j < MM / 128 - 1; ++j) {
    int k0 = j * 128;
    compute(lA0, lB0);
    BARRIER();
    stage(k0 + 128, lA0, lB0);
    asm volatile("s_waitcnt vmcnt(8)" ::: "memory");
    BARRIER();
    compute(lA1, lB1);
    BARRIER();
    stage(k0 + 192, lA1, lB1);
    asm volatile("s_waitcnt vmcnt(8)" ::: "memory");
    BARRIER();
  }
  compute(lA0, lB0);
  asm volatile("s_waitcnt vmcnt(0)" ::: "memory");
  BARRIER();
  compute(lA1, lB1);

#pragma unroll
  for (int i = 0; i < 4; ++i) {
#pragma unroll
    for (int c = 0; c < 4; ++c) {
#pragma unroll
      for (int rg = 0; rg < 4; ++rg) {
        int row = row0 + rw + i * 16 + lr4 + rg;
        if (row < n)
          Yd[(size_t)row * DD + d0 + cw + c * 16 + lc] = f2bf(acc[i][c][rg]);
      }
    }
  }
}

// ---------------------------------------------------------------------------
// Combine: out[t][d] = gate[t]*Ys[t][d] + w0*Yr[p0][d] + w1*Yr[p1][d]
// ---------------------------------------------------------------------------
__global__ __launch_bounds__(256) void combine_kernel(
    const unsigned short* __restrict__ Yr, const unsigned short* __restrict__ Ys,
    const int* __restrict__ slotOf, const float* __restrict__ topk_w,
    const float* __restrict__ gate, float* __restrict__ out)
{
  int t = blockIdx.x;
  int d0 = threadIdx.x * 8;
  int p0 = slotOf[t * 2], p1 = slotOf[t * 2 + 1];
  float w0 = topk_w[t * 2], w1 = topk_w[t * 2 + 1], g = gate[t];
  short8 a = *(const short8*)&Yr[(size_t)p0 * DD + d0];
  short8 b = *(const short8*)&Yr[(size_t)p1 * DD + d0];
  short8 s = *(const short8*)&Ys[(size_t)t * DD + d0];
  float r[8];
#pragma unroll
  for (int j = 0; j < 8; ++j)
    r[j] = w0 * bf2f((unsigned short)a[j]) + w1 * bf2f((unsigned short)b[j])
         + g * bf2f((unsigned short)s[j]);
  float4 o0 = {r[0], r[1], r[2], r[3]};
  float4 o1 = {r[4], r[5], r[6], r[7]};
  float* op = out + (size_t)t * DD + d0;
  *(float4*)op = o0;
  *(float4*)(op + 4) = o1;
}

// ---------------------------------------------------------------------------
extern "C" void kernel_launch(void* const* d_in, const int* in_sizes, int n_in,
                              void* d_out, int out_size, void* d_ws, size_t ws_size,
                              hipStream_t stream) {
  const float* x    = (const float*)d_in[0];
  const float* wr   = (const float*)d_in[1];
  const float* wi0  = (const float*)d_in[2];
  const float* wi1  = (const float*)d_in[3];
  const float* wo   = (const float*)d_in[4];
  const float* swi0 = (const float*)d_in[5];
  const float* swi1 = (const float*)d_in[6];
  const float* swo  = (const float*)d_in[7];
  const float* wg   = (const float*)d_in[8];
  float* out = (float*)d_out;

  char* ws = (char*)d_ws;
  int*   cnt    = (int*)(ws + 0);
  int*   fillc  = (int*)(ws + 64);
  int*   offs   = (int*)(ws + 128);
  int*   topk_i = (int*)(ws + 1024);
  float* topk_w = (float*)(ws + 33792);
  int*   btok   = (int*)(ws + 66560);
  float* gate   = (float*)(ws + 132096);
  int*   slotOf = (int*)(ws + 148480);
  int*   cnt_part   = (int*)(ws + 262144);                 // 32 KB
  float* proxy_part = (float*)(ws + 294912);               // 32 KB
  unsigned short* xb    = (unsigned short*)(ws + 1048576);   // 16 MB; reused as Ys
  unsigned short* H     = (unsigned short*)(ws + 17825792);  // 8 MB
  unsigned short* Hs    = (unsigned short*)(ws + 26214400);  // 4 MB
  unsigned short* wi0T  = (unsigned short*)(ws + 30408704);  // 16 MB; reused as Yr (+wi1T)
  unsigned short* wi1T  = (unsigned short*)(ws + 47185920);  // 16 MB
  unsigned short* woT   = (unsigned short*)(ws + 63963136);  // 16 MB
  unsigned short* swi0T = (unsigned short*)(ws + 80740352);  // 2 MB
  unsigned short* swi1T = (unsigned short*)(ws + 82837504);  // 2 MB
  unsigned short* swoT  = (unsigned short*)(ws + 84934656);  // 2 MB
  unsigned short* Ys = xb;
  unsigned short* Yr = wi0T;

  hipMemsetAsync(ws, 0, 256, stream);

  prep_kernel<<<27 * 64 + TT / 4, 256, 0, stream>>>(
      wi0, wi1, wo, swi0, swi1, swo, wi0T, wi1T, woT, swi0T, swi1T, swoT,
      x, wr, wg, xb, topk_i, topk_w, gate, cnt_part, proxy_part);
  offsets_loss_kernel<<<1, 256, 0, stream>>>(
      cnt_part, proxy_part, cnt, offs, out + (size_t)TT * DD);
  fill_kernel<<<(TT * 2) / 256, 256, 0, stream>>>(topk_i, offs, fillc, btok, slotOf);

  gemm1_kernel<<<dim3(MM / 64, 32, EE + 1), 256, 0, stream>>>(
      xb, wi0T, wi1T, swi0T, swi1T, H, Hs, btok, cnt, offs);
  gemm2_kernel<<<dim3(DD / 128, 32, EE + 1), 256, 0, stream>>>(
      H, Hs, woT, swoT, Yr, Ys, cnt, offs);
  combine_kernel<<<TT, 256, 0, stream>>>(Yr, Ys, slotOf, topk_w, gate, out);
}

// Round 14
// 196.228 us; speedup vs baseline: 1.1068x; 1.0034x over previous
//
#include <hip/hip_runtime.h>
#include <hip/hip_bf16.h>
#include <math.h>

#define TT 4096
#define DD 2048
#define MM 512
#define EE 8

typedef __attribute__((ext_vector_type(8))) short short8;
typedef __attribute__((ext_vector_type(4))) float f32x4;

// raw barrier: inline asm with memory clobber = HW barrier + compiler fence,
// WITHOUT __syncthreads' implicit s_waitcnt vmcnt(0) drain.
#define BARRIER() asm volatile("s_barrier" ::: "memory")
// Drain this wave's LDS reads BEFORE signalling a barrier. The WAR guarantee
// ("barrier after compute => safe to DMA-overwrite the buffer") requires
// reads COMPLETE, not merely issued: hipcc attaches lgkmcnt waits to the
// MFMA uses, and register-only MFMAs (with their waits) can sink past the
// barrier asm (memory clobber doesn't order them) -> a pending ds_read
// samples the NEXT tile. Confirmed in R12: R9/R11 failed without this,
// passed with it. R3/R8's schedule was lucky; this makes it structural.
#define LDS_READS_DONE() asm volatile("s_waitcnt lgkmcnt(0)" ::: "memory")

__device__ __forceinline__ unsigned short f2bf(float f) {
  union { float f; unsigned u; } v; v.f = f;
  unsigned u = v.u;
  unsigned r = u + 0x7FFFu + ((u >> 16) & 1u);
  return (unsigned short)(r >> 16);
}

__device__ __forceinline__ float bf2f(unsigned short u) {
  union { unsigned u; float f; } v; v.u = ((unsigned)u) << 16;
  return v.f;
}

__device__ __forceinline__ int imin(int a, int b) { return a < b ? a : b; }

__device__ __forceinline__ void gld16(const void* g, void* l) {
  __builtin_amdgcn_global_load_lds(
      (const __attribute__((address_space(1))) void*)g,
      (__attribute__((address_space(3))) void*)l, 16, 0, 0);
}

// ---------------------------------------------------------------------------
// prep:
// blocks [0, 27*64): weight convert+transpose, 1 tile/wave, 8x8/lane.
// blocks [27*64, +1024): router, per-block partials (no global atomics).
// ROUND-14 FIX (rule #20): the router FMA loop is now FULLY UNROLLED —
// previously xv[i]/wgv[i] were runtime-indexed in a rolled loop, forcing
// the 64-float arrays to SCRATCH (global memory). Evidence: VGPR_Count=72,
// impossible with the arrays in registers. Scratch round-trips per
// iteration were the router's hidden latency (and why wr-coalescing and
// the transpose rewrites were all null). FMA order unchanged.
// ---------------------------------------------------------------------------
__global__ __launch_bounds__(256) void prep_kernel(
    const float* __restrict__ wi0, const float* __restrict__ wi1,
    const float* __restrict__ wo, const float* __restrict__ swi0,
    const float* __restrict__ swi1, const float* __restrict__ swo,
    unsigned short* __restrict__ wi0T, unsigned short* __restrict__ wi1T,
    unsigned short* __restrict__ woT, unsigned short* __restrict__ swi0T,
    unsigned short* __restrict__ swi1T, unsigned short* __restrict__ swoT,
    const float* __restrict__ x, const float* __restrict__ wr,
    const float* __restrict__ wg, unsigned short* __restrict__ xb,
    int* __restrict__ topk_i, float* __restrict__ topk_w,
    float* __restrict__ gate, int* __restrict__ cnt_part,
    float* __restrict__ proxy_part)
{
  __shared__ float s_proxy[EE];
  __shared__ int s_cnt[EE];
  int b = blockIdx.x;
  int tid = threadIdx.x;

  if (b < 27 * 64) {
    int slice = b >> 6, q = b & 63;
    const float* s; unsigned short* d;
    int R, C, tcb;
    if (slice < 8)       { s = wi0 + (size_t)slice * DD * MM;        d = wi0T + (size_t)slice * DD * MM;        R = DD; C = MM; tcb = 3; }
    else if (slice < 16) { s = wi1 + (size_t)(slice - 8) * DD * MM;  d = wi1T + (size_t)(slice - 8) * DD * MM;  R = DD; C = MM; tcb = 3; }
    else if (slice < 24) { s = wo + (size_t)(slice - 16) * MM * DD;  d = woT + (size_t)(slice - 16) * MM * DD;  R = MM; C = DD; tcb = 5; }
    else if (slice == 24){ s = swi0; d = swi0T; R = DD; C = MM; tcb = 3; }
    else if (slice == 25){ s = swi1; d = swi1T; R = DD; C = MM; tcb = 3; }
    else                 { s = swo;  d = swoT;  R = MM; C = DD; tcb = 5; }
    int ncmask = (1 << tcb) - 1;

    int wv = tid >> 6, lane = tid & 63;
    int t = q * 4 + wv;
    int c0 = (t & ncmask) * 64, r0 = (t >> tcb) * 64;
    int r8 = (lane >> 3) * 8;
    int c8 = (lane & 7) * 8;

    const float* sp = s + (size_t)(r0 + r8) * C + (c0 + c8);
    float4 v[8][2];
#pragma unroll
    for (int j = 0; j < 8; ++j) {
      v[j][0] = *(const float4*)&sp[(size_t)j * C];
      v[j][1] = *(const float4*)&sp[(size_t)j * C + 4];
    }
    __builtin_amdgcn_sched_barrier(0);
    unsigned short u[8][8];
#pragma unroll
    for (int j = 0; j < 8; ++j) {
      u[j][0] = f2bf(v[j][0].x); u[j][1] = f2bf(v[j][0].y);
      u[j][2] = f2bf(v[j][0].z); u[j][3] = f2bf(v[j][0].w);
      u[j][4] = f2bf(v[j][1].x); u[j][5] = f2bf(v[j][1].y);
      u[j][6] = f2bf(v[j][1].z); u[j][7] = f2bf(v[j][1].w);
    }
    unsigned short* dp = d + (size_t)(c0 + c8) * R + (r0 + r8);
#pragma unroll
    for (int c = 0; c < 8; ++c) {
      short8 o;
#pragma unroll
      for (int j = 0; j < 8; ++j) o[j] = (short)u[j][c];
      *(short8*)&dp[(size_t)c * R] = o;
    }
    return;
  }

  // ---- router part: per-block partials, no global atomics ----
  int rb = b - 27 * 64;
  if (tid < EE) { s_proxy[tid] = 0.f; s_cnt[tid] = 0; }
  __syncthreads();
  int wave = tid >> 6, lane = tid & 63;
  int t = rb * 4 + wave;
  const float* xr = x + (size_t)t * DD;
  unsigned short* xbr = xb + (size_t)t * DD;

  float xv[32], wgv[32];
#pragma unroll
  for (int i = 0; i < 32; ++i) xv[i] = xr[lane + i * 64];
#pragma unroll
  for (int i = 0; i < 32; ++i) wgv[i] = wg[lane + i * 64];
#pragma unroll
  for (int i = 0; i < 32; ++i) xbr[lane + i * 64] = f2bf(xv[i]);

  float p[EE];
#pragma unroll
  for (int e = 0; e < EE; ++e) p[e] = 0.f;
  float pg = 0.f;
#pragma unroll
  for (int i = 0; i < DD / 64; ++i) {
    int d = lane + i * 64;
    const float* w = wr + d * EE;
#pragma unroll
    for (int e = 0; e < EE; ++e) p[e] = fmaf(xv[i], w[e], p[e]);
    pg = fmaf(xv[i], wgv[i], pg);
  }
#pragma unroll
  for (int e = 0; e < EE; ++e) {
#pragma unroll
    for (int off = 32; off; off >>= 1) p[e] += __shfl_xor(p[e], off);
  }
#pragma unroll
  for (int off = 32; off; off >>= 1) pg += __shfl_xor(pg, off);

  if (lane == 0) {
    float mx = p[0];
#pragma unroll
    for (int e = 1; e < EE; ++e) mx = fmaxf(mx, p[e]);
    float pr[EE]; float s = 0.f;
#pragma unroll
    for (int e = 0; e < EE; ++e) { pr[e] = __expf(p[e] - mx); s += pr[e]; }
    float inv = 1.f / s;
#pragma unroll
    for (int e = 0; e < EE; ++e) pr[e] *= inv;
    int i0 = 0;
#pragma unroll
    for (int e = 1; e < EE; ++e) if (p[e] > p[i0]) i0 = e;
    int i1 = (i0 == 0) ? 1 : 0;
#pragma unroll
    for (int e = 0; e < EE; ++e) if (e != i0 && p[e] > p[i1]) i1 = e;
    float w0 = pr[i0], w1 = pr[i1], s2 = w0 + w1;
    topk_i[t * 2] = i0; topk_i[t * 2 + 1] = i1;
    topk_w[t * 2] = w0 / s2; topk_w[t * 2 + 1] = w1 / s2;
    gate[t] = 1.f / (1.f + __expf(-pg));
    atomicAdd(&s_cnt[i0], 1);
    atomicAdd(&s_cnt[i1], 1);
#pragma unroll
    for (int e = 0; e < EE; ++e) atomicAdd(&s_proxy[e], pr[e]);
  }
  __syncthreads();
  if (tid < EE) {
    cnt_part[rb * EE + tid] = s_cnt[tid];
    proxy_part[rb * EE + tid] = s_proxy[tid];
  }
}

// ---------------------------------------------------------------------------
// offsets_loss: reduce 1024 per-block partials -> cnt/offs/loss. 1 block,
// 256 threads (32 reduction groups x 8 experts), 64KB L2-resident traffic.
// ---------------------------------------------------------------------------
__global__ __launch_bounds__(256) void offsets_loss_kernel(
    const int* __restrict__ cnt_part, const float* __restrict__ proxy_part,
    int* __restrict__ cnt, int* __restrict__ offs, float* __restrict__ out_loss)
{
  __shared__ int sc[256];
  __shared__ float sp[256];
  int tid = threadIdx.x;
  int e = tid & 7, g = tid >> 3;       // 32 groups per expert
  int ci = 0; float pi = 0.f;
  for (int b = g; b < TT / 4; b += 32) {
    ci += cnt_part[b * EE + e];
    pi += proxy_part[b * EE + e];
  }
  sc[tid] = ci; sp[tid] = pi;
  __syncthreads();
  if (tid < EE) {
    int c = 0; float p = 0.f;
    for (int g2 = 0; g2 < 32; ++g2) { c += sc[g2 * 8 + tid]; p += sp[g2 * 8 + tid]; }
    cnt[tid] = c;
    sc[tid] = c; sp[tid] = p;          // same-wave lockstep: loop reads done
  }
  __syncthreads();
  if (tid == 0) {
    int acc = 0; float l = 0.f;
    for (int e2 = 0; e2 < EE; ++e2) {
      offs[e2] = acc; acc += sc[e2];
      l += (float)sc[e2] * sp[e2];
    }
    out_loss[0] = l * (0.01f * (float)EE) / ((float)TT * (float)TT);
  }
}

// ---------------------------------------------------------------------------
// fill: per-block LDS histogram; ONE global atomic per expert per block
// (256 total). Intra-block rank from the LDS atomic's return value.
// ---------------------------------------------------------------------------
__global__ __launch_bounds__(256) void fill_kernel(
    const int* __restrict__ topk_i, const int* __restrict__ offs,
    int* __restrict__ fillc, int* __restrict__ btok, int* __restrict__ slotOf)
{
  __shared__ int lh[EE], gb[EE];
  int tid = threadIdx.x;
  int idx = blockIdx.x * 256 + tid;    // grid = 8192/256 exact
  if (tid < EE) lh[tid] = 0;
  __syncthreads();
  int e = topk_i[idx];
  int r = atomicAdd(&lh[e], 1);        // intra-block rank
  __syncthreads();
  if (tid < EE) gb[tid] = atomicAdd(&fillc[tid], lh[tid]);
  __syncthreads();
  int p = offs[e] + gb[e] + r;
  btok[p] = idx >> 1;
  slotOf[idx] = p;
}

// ---------------------------------------------------------------------------
// GEMM1: H[row][m] = silu(x@wi0)*(x@wi1). Round-8 structure (session best:
// 85us, 0 bank conflicts, MfmaUtil ~26% = its LDS-read-BW ceiling at 85B/cyc
// ds_read_b128): tile 128 rows x (64 m-cols x 2 mats), BK=64; counted-vmcnt
// double-buffer; raw s_barrier; LDS_READS_DONE() closes the R12-confirmed
// WAR race.
// ---------------------------------------------------------------------------
__global__ __launch_bounds__(256) void gemm1_kernel(
    const unsigned short* __restrict__ xb,
    const unsigned short* __restrict__ wi0T, const unsigned short* __restrict__ wi1T,
    const unsigned short* __restrict__ swi0T, const unsigned short* __restrict__ swi1T,
    unsigned short* __restrict__ H, unsigned short* __restrict__ Hs,
    const int* __restrict__ btok, const int* __restrict__ cnt, const int* __restrict__ offs)
{
  __shared__ __align__(16) unsigned short lA0[128 * 64];   // 16 KB
  __shared__ __align__(16) unsigned short lA1[128 * 64];   // 16 KB
  __shared__ __align__(16) unsigned short lB0[128 * 64];   // 16 KB (0-63 mat0, 64-127 mat1)
  __shared__ __align__(16) unsigned short lB1[128 * 64];   // 16 KB
  int z = blockIdx.z;
  const unsigned short *w0, *w1;
  const int* tok = nullptr;
  unsigned short* Ho;
  int n;
  if (z < EE) {
    n = cnt[z];
    int rb = offs[z];
    tok = btok + rb;
    w0 = wi0T + (size_t)z * (DD * MM);
    w1 = wi1T + (size_t)z * (DD * MM);
    Ho = H + (size_t)rb * MM;
  } else { n = TT; w0 = swi0T; w1 = swi1T; Ho = Hs; }
  int row0 = blockIdx.y * 128;
  if (row0 >= n) return;
  int m0 = blockIdx.x * 64;
  int tid = threadIdx.x, lane = tid & 63, wv = tid >> 6;

  int lsub = lane >> 3;            // 0..7 = row&7
  int chl = (lane & 7) ^ lsub;     // logical chunk for this lane's cell

  const unsigned short* gA[4];
  const unsigned short* gB[4];
#pragma unroll
  for (int c = 0; c < 4; ++c) {
    int row = c * 32 + wv * 8 + lsub;                 // 0..127
    int tr;
    if (tok) tr = tok[imin(row0 + row, n - 1)];
    else     tr = row0 + row;
    gA[c] = xb + (size_t)tr * DD + chl * 8;
    int mat = row >> 6, col = row & 63;
    const unsigned short* wsel = mat ? w1 : w0;
    gB[c] = wsel + (size_t)(m0 + col) * DD + chl * 8;
  }

  int rw = (wv & 1) * 64;          // wave row base
  int cg = (wv >> 1) * 32;         // wave per-mat col base
  int fr = lane & 15;
  int grp = lane >> 4;             // 0..3
  int lr4 = (lane >> 4) * 4, lc = lane & 15;

  f32x4 acc[4][4];
  f32x4 zf = {0.f, 0.f, 0.f, 0.f};
#pragma unroll
  for (int i = 0; i < 4; ++i)
#pragma unroll
    for (int c = 0; c < 4; ++c) acc[i][c] = zf;

  auto stage = [&](int kk, unsigned short* la, unsigned short* lb) {
#pragma unroll
    for (int c = 0; c < 4; ++c) gld16(gA[c] + kk, la + c * 2048 + wv * 512);
#pragma unroll
    for (int c = 0; c < 4; ++c) gld16(gB[c] + kk, lb + c * 2048 + wv * 512);
  };
  auto compute = [&](const unsigned short* la, const unsigned short* lb) {
#pragma unroll
    for (int s = 0; s < 2; ++s) {
      int cq = s * 4 + grp;        // logical chunk for this frag read
      short8 af[4], bf[4];
#pragma unroll
      for (int i = 0; i < 4; ++i) {
        int row = rw + i * 16 + fr;
        af[i] = *(const short8*)&la[row * 64 + ((cq ^ (row & 7)) * 8)];
      }
#pragma unroll
      for (int c = 0; c < 4; ++c) {
        int rowb = (c >> 1) * 64 + cg + (c & 1) * 16 + fr;
        bf[c] = *(const short8*)&lb[rowb * 64 + ((cq ^ (rowb & 7)) * 8)];
      }
#pragma unroll
      for (int i = 0; i < 4; ++i)
#pragma unroll
        for (int c = 0; c < 4; ++c)
          acc[i][c] = __builtin_amdgcn_mfma_f32_16x16x32_bf16(af[i], bf[c], acc[i][c], 0, 0, 0);
    }
    LDS_READS_DONE();              // reads complete before the next barrier
  };

  // prologue: tiles 0 and 1 staged; full drain (order-independent, safe)
  stage(0, lA0, lB0);
  stage(64, lA1, lB1);
  asm volatile("s_waitcnt vmcnt(0)" ::: "memory");
  BARRIER();

#pragma unroll 1
  for (int j = 0; j < DD / 128 - 1; ++j) {
    int k0 = j * 128;
    compute(lA0, lB0);                 // tile 2j
    BARRIER();                         // all waves DONE reading buf0
    stage(k0 + 128, lA0, lB0);         // issue tile 2j+2
    asm volatile("s_waitcnt vmcnt(8)" ::: "memory");  // tile 2j+1 landed
    BARRIER();
    compute(lA1, lB1);                 // tile 2j+1
    BARRIER();
    stage(k0 + 192, lA1, lB1);         // issue tile 2j+3
    asm volatile("s_waitcnt vmcnt(8)" ::: "memory");  // tile 2j+2 landed
    BARRIER();
  }
  // epilogue: tiles NT-2 (buf0, already waited) and NT-1 (buf1)
  compute(lA0, lB0);
  asm volatile("s_waitcnt vmcnt(0)" ::: "memory");
  BARRIER();
  compute(lA1, lB1);

#pragma unroll
  for (int i = 0; i < 4; ++i) {
#pragma unroll
    for (int c = 0; c < 2; ++c) {
#pragma unroll
      for (int rg = 0; rg < 4; ++rg) {
        int row = row0 + rw + i * 16 + lr4 + rg;
        if (row < n) {
          float a0 = acc[i][c][rg];
          float a1 = acc[i][c + 2][rg];
          float h = a0 / (1.f + __expf(-a0)) * a1;
          Ho[(size_t)row * MM + m0 + cg + c * 16 + lc] = f2bf(h);
        }
      }
    }
  }
}

// ---------------------------------------------------------------------------
// GEMM2: Y = H @ woT. Round-8 structure + LDS_READS_DONE(). Tile 128 rows
// x 128 d-cols, BK=64; counted-vmcnt double-buffer; raw s_barrier.
// ---------------------------------------------------------------------------
__global__ __launch_bounds__(256) void gemm2_kernel(
    const unsigned short* __restrict__ H, const unsigned short* __restrict__ Hs,
    const unsigned short* __restrict__ woT, const unsigned short* __restrict__ swoT,
    unsigned short* __restrict__ Yr, unsigned short* __restrict__ Ys,
    const int* __restrict__ cnt, const int* __restrict__ offs)
{
  __shared__ __align__(16) unsigned short lA0[128 * 64];
  __shared__ __align__(16) unsigned short lA1[128 * 64];
  __shared__ __align__(16) unsigned short lB0[128 * 64];   // rows = out cols
  __shared__ __align__(16) unsigned short lB1[128 * 64];
  int z = blockIdx.z;
  int n, rb;
  const unsigned short *Hb, *wb;
  unsigned short* Yd;
  if (z < EE) { n = cnt[z]; rb = offs[z]; Hb = H + (size_t)rb * MM; wb = woT + (size_t)z * (DD * MM); Yd = Yr + (size_t)rb * DD; }
  else        { n = TT; rb = 0; Hb = Hs; wb = swoT; Yd = Ys; }
  int row0 = blockIdx.y * 128;
  if (row0 >= n) return;
  int d0 = blockIdx.x * 128;
  int tid = threadIdx.x, lane = tid & 63, wv = tid >> 6;

  int lsub = lane >> 3;
  int chl = (lane & 7) ^ lsub;

  const unsigned short* gA[4];
  const unsigned short* gB[4];
#pragma unroll
  for (int c = 0; c < 4; ++c) {
    int row = c * 32 + wv * 8 + lsub;
    int sr = imin(row0 + row, n - 1);
    gA[c] = Hb + (size_t)sr * MM + chl * 8;
    gB[c] = wb + (size_t)(d0 + row) * MM + chl * 8;
  }

  int rw = (wv & 1) * 64;
  int cw = (wv >> 1) * 64;
  int fr = lane & 15;
  int grp = lane >> 4;
  int lr4 = (lane >> 4) * 4, lc = lane & 15;

  f32x4 acc[4][4];
  f32x4 zf = {0.f, 0.f, 0.f, 0.f};
#pragma unroll
  for (int i = 0; i < 4; ++i)
#pragma unroll
    for (int c = 0; c < 4; ++c) acc[i][c] = zf;

  auto stage = [&](int kk, unsigned short* la, unsigned short* lb) {
#pragma unroll
    for (int c = 0; c < 4; ++c) gld16(gA[c] + kk, la + c * 2048 + wv * 512);
#pragma unroll
    for (int c = 0; c < 4; ++c) gld16(gB[c] + kk, lb + c * 2048 + wv * 512);
  };
  auto compute = [&](const unsigned short* la, const unsigned short* lb) {
#pragma unroll
    for (int s = 0; s < 2; ++s) {
      int cq = s * 4 + grp;
      short8 af[4], bf[4];
#pragma unroll
      for (int i = 0; i < 4; ++i) {
        int row = rw + i * 16 + fr;
        af[i] = *(const short8*)&la[row * 64 + ((cq ^ (row & 7)) * 8)];
      }
#pragma unroll
      for (int c = 0; c < 4; ++c) {
        int rowb = cw + c * 16 + fr;
        bf[c] = *(const short8*)&lb[rowb * 64 + ((cq ^ (rowb & 7)) * 8)];
      }
#pragma unroll
      for (int i = 0; i < 4; ++i)
#pragma unroll
        for (int c = 0; c < 4; ++c)
          acc[i][c] = __builtin_amdgcn_mfma_f32_16x16x32_bf16(af[i], bf[c], acc[i][c], 0, 0, 0);
    }
    LDS_READS_DONE();
  };

  // prologue: full drain (order-independent, safe)
  stage(0, lA0, lB0);
  stage(64, lA1, lB1);
  asm volatile("s_waitcnt vmcnt(0)" ::: "memory");
  BARRIER();

#pragma unroll 1
  for (int j = 0; j < MM / 128 - 1; ++j) {
    int k0 = j * 128;
    compute(lA0, lB0);
    BARRIER();
    stage(k0 + 128, lA0, lB0);
    asm volatile("s_waitcnt vmcnt(8)" ::: "memory");
    BARRIER();
    compute(lA1, lB1);
    BARRIER();
    stage(k0 + 192, lA1, lB1);
    asm volatile("s_waitcnt vmcnt(8)" ::: "memory");
    BARRIER();
  }
  compute(lA0, lB0);
  asm volatile("s_waitcnt vmcnt(0)" ::: "memory");
  BARRIER();
  compute(lA1, lB1);

#pragma unroll
  for (int i = 0; i < 4; ++i) {
#pragma unroll
    for (int c = 0; c < 4; ++c) {
#pragma unroll
      for (int rg = 0; rg < 4; ++rg) {
        int row = row0 + rw + i * 16 + lr4 + rg;
        if (row < n)
          Yd[(size_t)row * DD + d0 + cw + c * 16 + lc] = f2bf(acc[i][c][rg]);
      }
    }
  }
}

// ---------------------------------------------------------------------------
// Combine: out[t][d] = gate[t]*Ys[t][d] + w0*Yr[p0][d] + w1*Yr[p1][d]
// ---------------------------------------------------------------------------
__global__ __launch_bounds__(256) void combine_kernel(
    const unsigned short* __restrict__ Yr, const unsigned short* __restrict__ Ys,
    const int* __restrict__ slotOf, const float* __restrict__ topk_w,
    const float* __restrict__ gate, float* __restrict__ out)
{
  int t = blockIdx.x;
  int d0 = threadIdx.x * 8;
  int p0 = slotOf[t * 2], p1 = slotOf[t * 2 + 1];
  float w0 = topk_w[t * 2], w1 = topk_w[t * 2 + 1], g = gate[t];
  short8 a = *(const short8*)&Yr[(size_t)p0 * DD + d0];
  short8 b = *(const short8*)&Yr[(size_t)p1 * DD + d0];
  short8 s = *(const short8*)&Ys[(size_t)t * DD + d0];
  float r[8];
#pragma unroll
  for (int j = 0; j < 8; ++j)
    r[j] = w0 * bf2f((unsigned short)a[j]) + w1 * bf2f((unsigned short)b[j])
         + g * bf2f((unsigned short)s[j]);
  float4 o0 = {r[0], r[1], r[2], r[3]};
  float4 o1 = {r[4], r[5], r[6], r[7]};
  float* op = out + (size_t)t * DD + d0;
  *(float4*)op = o0;
  *(float4*)(op + 4) = o1;
}

// ---------------------------------------------------------------------------
extern "C" void kernel_launch(void* const* d_in, const int* in_sizes, int n_in,
                              void* d_out, int out_size, void* d_ws, size_t ws_size,
                              hipStream_t stream) {
  const float* x    = (const float*)d_in[0];
  const float* wr   = (const float*)d_in[1];
  const float* wi0  = (const float*)d_in[2];
  const float* wi1  = (const float*)d_in[3];
  const float* wo   = (const float*)d_in[4];
  const float* swi0 = (const float*)d_in[5];
  const float* swi1 = (const float*)d_in[6];
  const float* swo  = (const float*)d_in[7];
  const float* wg   = (const float*)d_in[8];
  float* out = (float*)d_out;

  char* ws = (char*)d_ws;
  int*   cnt    = (int*)(ws + 0);
  int*   fillc  = (int*)(ws + 64);
  int*   offs   = (int*)(ws + 128);
  int*   topk_i = (int*)(ws + 1024);
  float* topk_w = (float*)(ws + 33792);
  int*   btok   = (int*)(ws + 66560);
  float* gate   = (float*)(ws + 132096);
  int*   slotOf = (int*)(ws + 148480);
  int*   cnt_part   = (int*)(ws + 262144);                 // 32 KB
  float* proxy_part = (float*)(ws + 294912);               // 32 KB
  unsigned short* xb    = (unsigned short*)(ws + 1048576);   // 16 MB; reused as Ys
  unsigned short* H     = (unsigned short*)(ws + 17825792);  // 8 MB
  unsigned short* Hs    = (unsigned short*)(ws + 26214400);  // 4 MB
  unsigned short* wi0T  = (unsigned short*)(ws + 30408704);  // 16 MB; reused as Yr (+wi1T)
  unsigned short* wi1T  = (unsigned short*)(ws + 47185920);  // 16 MB
  unsigned short* woT   = (unsigned short*)(ws + 63963136);  // 16 MB
  unsigned short* swi0T = (unsigned short*)(ws + 80740352);  // 2 MB
  unsigned short* swi1T = (unsigned short*)(ws + 82837504);  // 2 MB
  unsigned short* swoT  = (unsigned short*)(ws + 84934656);  // 2 MB
  unsigned short* Ys = xb;
  unsigned short* Yr = wi0T;

  hipMemsetAsync(ws, 0, 256, stream);

  prep_kernel<<<27 * 64 + TT / 4, 256, 0, stream>>>(
      wi0, wi1, wo, swi0, swi1, swo, wi0T, wi1T, woT, swi0T, swi1T, swoT,
      x, wr, wg, xb, topk_i, topk_w, gate, cnt_part, proxy_part);
  offsets_loss_kernel<<<1, 256, 0, stream>>>(
      cnt_part, proxy_part, cnt, offs, out + (size_t)TT * DD);
  fill_kernel<<<(TT * 2) / 256, 256, 0, stream>>>(topk_i, offs, fillc, btok, slotOf);

  gemm1_kernel<<<dim3(MM / 64, 32, EE + 1), 256, 0, stream>>>(
      xb, wi0T, wi1T, swi0T, swi1T, H, Hs, btok, cnt, offs);
  gemm2_kernel<<<dim3(DD / 128, 32, EE + 1), 256, 0, stream>>>(
      H, Hs, woT, swoT, Yr, Ys, cnt, offs);
  combine_kernel<<<TT, 256, 0, stream>>>(Yr, Ys, slotOf, topk_w, gate, out);
}

// Round 15
// 191.913 us; speedup vs baseline: 1.1317x; 1.0225x over previous
//
#include <hip/hip_runtime.h>
#include <hip/hip_bf16.h>
#include <math.h>

#define TT 4096
#define DD 2048
#define MM 512
#define EE 8

typedef __attribute__((ext_vector_type(8))) short short8;
typedef __attribute__((ext_vector_type(4))) float f32x4;

// raw barrier: inline asm with memory clobber = HW barrier + compiler fence,
// WITHOUT __syncthreads' implicit s_waitcnt vmcnt(0) drain.
#define BARRIER() asm volatile("s_barrier" ::: "memory")
// Drain this wave's LDS reads BEFORE signalling a barrier. The WAR guarantee
// ("barrier after compute => safe to DMA-overwrite the buffer") requires
// reads COMPLETE, not merely issued: hipcc attaches lgkmcnt waits to the
// MFMA uses, and register-only MFMAs (with their waits) can sink past the
// barrier asm (memory clobber doesn't order them) -> a pending ds_read
// samples the NEXT tile. Confirmed in R12: R9/R11 failed without this,
// passed with it. R3/R8's schedule was lucky; this makes it structural.
#define LDS_READS_DONE() asm volatile("s_waitcnt lgkmcnt(0)" ::: "memory")

__device__ __forceinline__ unsigned short f2bf(float f) {
  union { float f; unsigned u; } v; v.f = f;
  unsigned u = v.u;
  unsigned r = u + 0x7FFFu + ((u >> 16) & 1u);
  return (unsigned short)(r >> 16);
}

__device__ __forceinline__ float bf2f(unsigned short u) {
  union { unsigned u; float f; } v; v.u = ((unsigned)u) << 16;
  return v.f;
}

__device__ __forceinline__ int imin(int a, int b) { return a < b ? a : b; }

__device__ __forceinline__ void gld16(const void* g, void* l) {
  __builtin_amdgcn_global_load_lds(
      (const __attribute__((address_space(1))) void*)g,
      (__attribute__((address_space(3))) void*)l, 16, 0, 0);
}

// ---------------------------------------------------------------------------
// prep — ROUND-15: ROUTER BLOCKS DISPATCH FIRST.
// blocks [0, 1024): router (long, latency-bound; all co-resident at 8
//   blocks/CU). blocks [1024, 1024+27*64): weight transpose (short,
//   BW-bound) backfills UNDER the router latency. Previous order ran
//   transpose first, serializing the phases — the invariant ~83us across
//   six prep implementations.
// ---------------------------------------------------------------------------
__global__ __launch_bounds__(256) void prep_kernel(
    const float* __restrict__ wi0, const float* __restrict__ wi1,
    const float* __restrict__ wo, const float* __restrict__ swi0,
    const float* __restrict__ swi1, const float* __restrict__ swo,
    unsigned short* __restrict__ wi0T, unsigned short* __restrict__ wi1T,
    unsigned short* __restrict__ woT, unsigned short* __restrict__ swi0T,
    unsigned short* __restrict__ swi1T, unsigned short* __restrict__ swoT,
    const float* __restrict__ x, const float* __restrict__ wr,
    const float* __restrict__ wg, unsigned short* __restrict__ xb,
    int* __restrict__ topk_i, float* __restrict__ topk_w,
    float* __restrict__ gate, int* __restrict__ cnt_part,
    float* __restrict__ proxy_part)
{
  __shared__ float s_proxy[EE];
  __shared__ int s_cnt[EE];
  int b = blockIdx.x;
  int tid = threadIdx.x;

  if (b >= TT / 4) {
    // ---- weight transpose: 1 tile per wave, 8x8 sub-tile per lane ----
    int tb = b - TT / 4;
    int slice = tb >> 6, q = tb & 63;
    const float* s; unsigned short* d;
    int R, C, tcb;
    if (slice < 8)       { s = wi0 + (size_t)slice * DD * MM;        d = wi0T + (size_t)slice * DD * MM;        R = DD; C = MM; tcb = 3; }
    else if (slice < 16) { s = wi1 + (size_t)(slice - 8) * DD * MM;  d = wi1T + (size_t)(slice - 8) * DD * MM;  R = DD; C = MM; tcb = 3; }
    else if (slice < 24) { s = wo + (size_t)(slice - 16) * MM * DD;  d = woT + (size_t)(slice - 16) * MM * DD;  R = MM; C = DD; tcb = 5; }
    else if (slice == 24){ s = swi0; d = swi0T; R = DD; C = MM; tcb = 3; }
    else if (slice == 25){ s = swi1; d = swi1T; R = DD; C = MM; tcb = 3; }
    else                 { s = swo;  d = swoT;  R = MM; C = DD; tcb = 5; }
    int ncmask = (1 << tcb) - 1;

    int wv = tid >> 6, lane = tid & 63;
    int t = q * 4 + wv;
    int c0 = (t & ncmask) * 64, r0 = (t >> tcb) * 64;
    int r8 = (lane >> 3) * 8;
    int c8 = (lane & 7) * 8;

    const float* sp = s + (size_t)(r0 + r8) * C + (c0 + c8);
    float4 v[8][2];
#pragma unroll
    for (int j = 0; j < 8; ++j) {
      v[j][0] = *(const float4*)&sp[(size_t)j * C];
      v[j][1] = *(const float4*)&sp[(size_t)j * C + 4];
    }
    __builtin_amdgcn_sched_barrier(0);
    unsigned short u[8][8];
#pragma unroll
    for (int j = 0; j < 8; ++j) {
      u[j][0] = f2bf(v[j][0].x); u[j][1] = f2bf(v[j][0].y);
      u[j][2] = f2bf(v[j][0].z); u[j][3] = f2bf(v[j][0].w);
      u[j][4] = f2bf(v[j][1].x); u[j][5] = f2bf(v[j][1].y);
      u[j][6] = f2bf(v[j][1].z); u[j][7] = f2bf(v[j][1].w);
    }
    unsigned short* dp = d + (size_t)(c0 + c8) * R + (r0 + r8);
#pragma unroll
    for (int c = 0; c < 8; ++c) {
      short8 o;
#pragma unroll
      for (int j = 0; j < 8; ++j) o[j] = (short)u[j][c];
      *(short8*)&dp[(size_t)c * R] = o;
    }
    return;
  }

  // ---- router part: per-block partials, no global atomics ----
  int rb = b;
  if (tid < EE) { s_proxy[tid] = 0.f; s_cnt[tid] = 0; }
  __syncthreads();
  int wave = tid >> 6, lane = tid & 63;
  int t = rb * 4 + wave;
  const float* xr = x + (size_t)t * DD;
  unsigned short* xbr = xb + (size_t)t * DD;

  float xv[32], wgv[32];
#pragma unroll
  for (int i = 0; i < 32; ++i) xv[i] = xr[lane + i * 64];
#pragma unroll
  for (int i = 0; i < 32; ++i) wgv[i] = wg[lane + i * 64];
#pragma unroll
  for (int i = 0; i < 32; ++i) xbr[lane + i * 64] = f2bf(xv[i]);

  float p[EE];
#pragma unroll
  for (int e = 0; e < EE; ++e) p[e] = 0.f;
  float pg = 0.f;
#pragma unroll
  for (int i = 0; i < DD / 64; ++i) {
    int d = lane + i * 64;
    const float* w = wr + d * EE;
#pragma unroll
    for (int e = 0; e < EE; ++e) p[e] = fmaf(xv[i], w[e], p[e]);
    pg = fmaf(xv[i], wgv[i], pg);
  }
#pragma unroll
  for (int e = 0; e < EE; ++e) {
#pragma unroll
    for (int off = 32; off; off >>= 1) p[e] += __shfl_xor(p[e], off);
  }
#pragma unroll
  for (int off = 32; off; off >>= 1) pg += __shfl_xor(pg, off);

  if (lane == 0) {
    float mx = p[0];
#pragma unroll
    for (int e = 1; e < EE; ++e) mx = fmaxf(mx, p[e]);
    float pr[EE]; float s = 0.f;
#pragma unroll
    for (int e = 0; e < EE; ++e) { pr[e] = __expf(p[e] - mx); s += pr[e]; }
    float inv = 1.f / s;
#pragma unroll
    for (int e = 0; e < EE; ++e) pr[e] *= inv;
    int i0 = 0;
#pragma unroll
    for (int e = 1; e < EE; ++e) if (p[e] > p[i0]) i0 = e;
    int i1 = (i0 == 0) ? 1 : 0;
#pragma unroll
    for (int e = 0; e < EE; ++e) if (e != i0 && p[e] > p[i1]) i1 = e;
    float w0 = pr[i0], w1 = pr[i1], s2 = w0 + w1;
    topk_i[t * 2] = i0; topk_i[t * 2 + 1] = i1;
    topk_w[t * 2] = w0 / s2; topk_w[t * 2 + 1] = w1 / s2;
    gate[t] = 1.f / (1.f + __expf(-pg));
    atomicAdd(&s_cnt[i0], 1);
    atomicAdd(&s_cnt[i1], 1);
#pragma unroll
    for (int e = 0; e < EE; ++e) atomicAdd(&s_proxy[e], pr[e]);
  }
  __syncthreads();
  if (tid < EE) {
    cnt_part[rb * EE + tid] = s_cnt[tid];
    proxy_part[rb * EE + tid] = s_proxy[tid];
  }
}

// ---------------------------------------------------------------------------
// offsets_loss: reduce 1024 per-block partials -> cnt/offs/loss. 1 block,
// 256 threads (32 reduction groups x 8 experts), 64KB L2-resident traffic.
// ---------------------------------------------------------------------------
__global__ __launch_bounds__(256) void offsets_loss_kernel(
    const int* __restrict__ cnt_part, const float* __restrict__ proxy_part,
    int* __restrict__ cnt, int* __restrict__ offs, float* __restrict__ out_loss)
{
  __shared__ int sc[256];
  __shared__ float sp[256];
  int tid = threadIdx.x;
  int e = tid & 7, g = tid >> 3;       // 32 groups per expert
  int ci = 0; float pi = 0.f;
  for (int b = g; b < TT / 4; b += 32) {
    ci += cnt_part[b * EE + e];
    pi += proxy_part[b * EE + e];
  }
  sc[tid] = ci; sp[tid] = pi;
  __syncthreads();
  if (tid < EE) {
    int c = 0; float p = 0.f;
    for (int g2 = 0; g2 < 32; ++g2) { c += sc[g2 * 8 + tid]; p += sp[g2 * 8 + tid]; }
    cnt[tid] = c;
    sc[tid] = c; sp[tid] = p;          // same-wave lockstep: loop reads done
  }
  __syncthreads();
  if (tid == 0) {
    int acc = 0; float l = 0.f;
    for (int e2 = 0; e2 < EE; ++e2) {
      offs[e2] = acc; acc += sc[e2];
      l += (float)sc[e2] * sp[e2];
    }
    out_loss[0] = l * (0.01f * (float)EE) / ((float)TT * (float)TT);
  }
}

// ---------------------------------------------------------------------------
// fill: per-block LDS histogram; ONE global atomic per expert per block
// (256 total). Intra-block rank from the LDS atomic's return value.
// ---------------------------------------------------------------------------
__global__ __launch_bounds__(256) void fill_kernel(
    const int* __restrict__ topk_i, const int* __restrict__ offs,
    int* __restrict__ fillc, int* __restrict__ btok, int* __restrict__ slotOf)
{
  __shared__ int lh[EE], gb[EE];
  int tid = threadIdx.x;
  int idx = blockIdx.x * 256 + tid;    // grid = 8192/256 exact
  if (tid < EE) lh[tid] = 0;
  __syncthreads();
  int e = topk_i[idx];
  int r = atomicAdd(&lh[e], 1);        // intra-block rank
  __syncthreads();
  if (tid < EE) gb[tid] = atomicAdd(&fillc[tid], lh[tid]);
  __syncthreads();
  int p = offs[e] + gb[e] + r;
  btok[p] = idx >> 1;
  slotOf[idx] = p;
}

// ---------------------------------------------------------------------------
// GEMM1: H[row][m] = silu(x@wi0)*(x@wi1). Round-8 structure (session best:
// 85us, 0 bank conflicts, MfmaUtil ~26% = its LDS-read-BW ceiling at 85B/cyc
// ds_read_b128): tile 128 rows x (64 m-cols x 2 mats), BK=64; counted-vmcnt
// double-buffer; raw s_barrier; LDS_READS_DONE() closes the R12-confirmed
// WAR race.
// ---------------------------------------------------------------------------
__global__ __launch_bounds__(256) void gemm1_kernel(
    const unsigned short* __restrict__ xb,
    const unsigned short* __restrict__ wi0T, const unsigned short* __restrict__ wi1T,
    const unsigned short* __restrict__ swi0T, const unsigned short* __restrict__ swi1T,
    unsigned short* __restrict__ H, unsigned short* __restrict__ Hs,
    const int* __restrict__ btok, const int* __restrict__ cnt, const int* __restrict__ offs)
{
  __shared__ __align__(16) unsigned short lA0[128 * 64];   // 16 KB
  __shared__ __align__(16) unsigned short lA1[128 * 64];   // 16 KB
  __shared__ __align__(16) unsigned short lB0[128 * 64];   // 16 KB (0-63 mat0, 64-127 mat1)
  __shared__ __align__(16) unsigned short lB1[128 * 64];   // 16 KB
  int z = blockIdx.z;
  const unsigned short *w0, *w1;
  const int* tok = nullptr;
  unsigned short* Ho;
  int n;
  if (z < EE) {
    n = cnt[z];
    int rb = offs[z];
    tok = btok + rb;
    w0 = wi0T + (size_t)z * (DD * MM);
    w1 = wi1T + (size_t)z * (DD * MM);
    Ho = H + (size_t)rb * MM;
  } else { n = TT; w0 = swi0T; w1 = swi1T; Ho = Hs; }
  int row0 = blockIdx.y * 128;
  if (row0 >= n) return;
  int m0 = blockIdx.x * 64;
  int tid = threadIdx.x, lane = tid & 63, wv = tid >> 6;

  int lsub = lane >> 3;            // 0..7 = row&7
  int chl = (lane & 7) ^ lsub;     // logical chunk for this lane's cell

  const unsigned short* gA[4];
  const unsigned short* gB[4];
#pragma unroll
  for (int c = 0; c < 4; ++c) {
    int row = c * 32 + wv * 8 + lsub;                 // 0..127
    int tr;
    if (tok) tr = tok[imin(row0 + row, n - 1)];
    else     tr = row0 + row;
    gA[c] = xb + (size_t)tr * DD + chl * 8;
    int mat = row >> 6, col = row & 63;
    const unsigned short* wsel = mat ? w1 : w0;
    gB[c] = wsel + (size_t)(m0 + col) * DD + chl * 8;
  }

  int rw = (wv & 1) * 64;          // wave row base
  int cg = (wv >> 1) * 32;         // wave per-mat col base
  int fr = lane & 15;
  int grp = lane >> 4;             // 0..3
  int lr4 = (lane >> 4) * 4, lc = lane & 15;

  f32x4 acc[4][4];
  f32x4 zf = {0.f, 0.f, 0.f, 0.f};
#pragma unroll
  for (int i = 0; i < 4; ++i)
#pragma unroll
    for (int c = 0; c < 4; ++c) acc[i][c] = zf;

  auto stage = [&](int kk, unsigned short* la, unsigned short* lb) {
#pragma unroll
    for (int c = 0; c < 4; ++c) gld16(gA[c] + kk, la + c * 2048 + wv * 512);
#pragma unroll
    for (int c = 0; c < 4; ++c) gld16(gB[c] + kk, lb + c * 2048 + wv * 512);
  };
  auto compute = [&](const unsigned short* la, const unsigned short* lb) {
#pragma unroll
    for (int s = 0; s < 2; ++s) {
      int cq = s * 4 + grp;        // logical chunk for this frag read
      short8 af[4], bf[4];
#pragma unroll
      for (int i = 0; i < 4; ++i) {
        int row = rw + i * 16 + fr;
        af[i] = *(const short8*)&la[row * 64 + ((cq ^ (row & 7)) * 8)];
      }
#pragma unroll
      for (int c = 0; c < 4; ++c) {
        int rowb = (c >> 1) * 64 + cg + (c & 1) * 16 + fr;
        bf[c] = *(const short8*)&lb[rowb * 64 + ((cq ^ (rowb & 7)) * 8)];
      }
#pragma unroll
      for (int i = 0; i < 4; ++i)
#pragma unroll
        for (int c = 0; c < 4; ++c)
          acc[i][c] = __builtin_amdgcn_mfma_f32_16x16x32_bf16(af[i], bf[c], acc[i][c], 0, 0, 0);
    }
    LDS_READS_DONE();              // reads complete before the next barrier
  };

  // prologue: tiles 0 and 1 staged; full drain (order-independent, safe)
  stage(0, lA0, lB0);
  stage(64, lA1, lB1);
  asm volatile("s_waitcnt vmcnt(0)" ::: "memory");
  BARRIER();

#pragma unroll 1
  for (int j = 0; j < DD / 128 - 1; ++j) {
    int k0 = j * 128;
    compute(lA0, lB0);                 // tile 2j
    BARRIER();                         // all waves DONE reading buf0
    stage(k0 + 128, lA0, lB0);         // issue tile 2j+2
    asm volatile("s_waitcnt vmcnt(8)" ::: "memory");  // tile 2j+1 landed
    BARRIER();
    compute(lA1, lB1);                 // tile 2j+1
    BARRIER();
    stage(k0 + 192, lA1, lB1);         // issue tile 2j+3
    asm volatile("s_waitcnt vmcnt(8)" ::: "memory");  // tile 2j+2 landed
    BARRIER();
  }
  // epilogue: tiles NT-2 (buf0, already waited) and NT-1 (buf1)
  compute(lA0, lB0);
  asm volatile("s_waitcnt vmcnt(0)" ::: "memory");
  BARRIER();
  compute(lA1, lB1);

#pragma unroll
  for (int i = 0; i < 4; ++i) {
#pragma unroll
    for (int c = 0; c < 2; ++c) {
#pragma unroll
      for (int rg = 0; rg < 4; ++rg) {
        int row = row0 + rw + i * 16 + lr4 + rg;
        if (row < n) {
          float a0 = acc[i][c][rg];
          float a1 = acc[i][c + 2][rg];
          float h = a0 / (1.f + __expf(-a0)) * a1;
          Ho[(size_t)row * MM + m0 + cg + c * 16 + lc] = f2bf(h);
        }
      }
    }
  }
}

// ---------------------------------------------------------------------------
// GEMM2: Y = H @ woT. Round-8 structure + LDS_READS_DONE(). Tile 128 rows
// x 128 d-cols, BK=64; counted-vmcnt double-buffer; raw s_barrier.
// ---------------------------------------------------------------------------
__global__ __launch_bounds__(256) void gemm2_kernel(
    const unsigned short* __restrict__ H, const unsigned short* __restrict__ Hs,
    const unsigned short* __restrict__ woT, const unsigned short* __restrict__ swoT,
    unsigned short* __restrict__ Yr, unsigned short* __restrict__ Ys,
    const int* __restrict__ cnt, const int* __restrict__ offs)
{
  __shared__ __align__(16) unsigned short lA0[128 * 64];
  __shared__ __align__(16) unsigned short lA1[128 * 64];
  __shared__ __align__(16) unsigned short lB0[128 * 64];   // rows = out cols
  __shared__ __align__(16) unsigned short lB1[128 * 64];
  int z = blockIdx.z;
  int n, rb;
  const unsigned short *Hb, *wb;
  unsigned short* Yd;
  if (z < EE) { n = cnt[z]; rb = offs[z]; Hb = H + (size_t)rb * MM; wb = woT + (size_t)z * (DD * MM); Yd = Yr + (size_t)rb * DD; }
  else        { n = TT; rb = 0; Hb = Hs; wb = swoT; Yd = Ys; }
  int row0 = blockIdx.y * 128;
  if (row0 >= n) return;
  int d0 = blockIdx.x * 128;
  int tid = threadIdx.x, lane = tid & 63, wv = tid >> 6;

  int lsub = lane >> 3;
  int chl = (lane & 7) ^ lsub;

  const unsigned short* gA[4];
  const unsigned short* gB[4];
#pragma unroll
  for (int c = 0; c < 4; ++c) {
    int row = c * 32 + wv * 8 + lsub;
    int sr = imin(row0 + row, n - 1);
    gA[c] = Hb + (size_t)sr * MM + chl * 8;
    gB[c] = wb + (size_t)(d0 + row) * MM + chl * 8;
  }

  int rw = (wv & 1) * 64;
  int cw = (wv >> 1) * 64;
  int fr = lane & 15;
  int grp = lane >> 4;
  int lr4 = (lane >> 4) * 4, lc = lane & 15;

  f32x4 acc[4][4];
  f32x4 zf = {0.f, 0.f, 0.f, 0.f};
#pragma unroll
  for (int i = 0; i < 4; ++i)
#pragma unroll
    for (int c = 0; c < 4; ++c) acc[i][c] = zf;

  auto stage = [&](int kk, unsigned short* la, unsigned short* lb) {
#pragma unroll
    for (int c = 0; c < 4; ++c) gld16(gA[c] + kk, la + c * 2048 + wv * 512);
#pragma unroll
    for (int c = 0; c < 4; ++c) gld16(gB[c] + kk, lb + c * 2048 + wv * 512);
  };
  auto compute = [&](const unsigned short* la, const unsigned short* lb) {
#pragma unroll
    for (int s = 0; s < 2; ++s) {
      int cq = s * 4 + grp;
      short8 af[4], bf[4];
#pragma unroll
      for (int i = 0; i < 4; ++i) {
        int row = rw + i * 16 + fr;
        af[i] = *(const short8*)&la[row * 64 + ((cq ^ (row & 7)) * 8)];
      }
#pragma unroll
      for (int c = 0; c < 4; ++c) {
        int rowb = cw + c * 16 + fr;
        bf[c] = *(const short8*)&lb[rowb * 64 + ((cq ^ (rowb & 7)) * 8)];
      }
#pragma unroll
      for (int i = 0; i < 4; ++i)
#pragma unroll
        for (int c = 0; c < 4; ++c)
          acc[i][c] = __builtin_amdgcn_mfma_f32_16x16x32_bf16(af[i], bf[c], acc[i][c], 0, 0, 0);
    }
    LDS_READS_DONE();
  };

  // prologue: full drain (order-independent, safe)
  stage(0, lA0, lB0);
  stage(64, lA1, lB1);
  asm volatile("s_waitcnt vmcnt(0)" ::: "memory");
  BARRIER();

#pragma unroll 1
  for (int j = 0; j < MM / 128 - 1; ++j) {
    int k0 = j * 128;
    compute(lA0, lB0);
    BARRIER();
    stage(k0 + 128, lA0, lB0);
    asm volatile("s_waitcnt vmcnt(8)" ::: "memory");
    BARRIER();
    compute(lA1, lB1);
    BARRIER();
    stage(k0 + 192, lA1, lB1);
    asm volatile("s_waitcnt vmcnt(8)" ::: "memory");
    BARRIER();
  }
  compute(lA0, lB0);
  asm volatile("s_waitcnt vmcnt(0)" ::: "memory");
  BARRIER();
  compute(lA1, lB1);

#pragma unroll
  for (int i = 0; i < 4; ++i) {
#pragma unroll
    for (int c = 0; c < 4; ++c) {
#pragma unroll
      for (int rg = 0; rg < 4; ++rg) {
        int row = row0 + rw + i * 16 + lr4 + rg;
        if (row < n)
          Yd[(size_t)row * DD + d0 + cw + c * 16 + lc] = f2bf(acc[i][c][rg]);
      }
    }
  }
}

// ---------------------------------------------------------------------------
// Combine: out[t][d] = gate[t]*Ys[t][d] + w0*Yr[p0][d] + w1*Yr[p1][d]
// ---------------------------------------------------------------------------
__global__ __launch_bounds__(256) void combine_kernel(
    const unsigned short* __restrict__ Yr, const unsigned short* __restrict__ Ys,
    const int* __restrict__ slotOf, const float* __restrict__ topk_w,
    const float* __restrict__ gate, float* __restrict__ out)
{
  int t = blockIdx.x;
  int d0 = threadIdx.x * 8;
  int p0 = slotOf[t * 2], p1 = slotOf[t * 2 + 1];
  float w0 = topk_w[t * 2], w1 = topk_w[t * 2 + 1], g = gate[t];
  short8 a = *(const short8*)&Yr[(size_t)p0 * DD + d0];
  short8 b = *(const short8*)&Yr[(size_t)p1 * DD + d0];
  short8 s = *(const short8*)&Ys[(size_t)t * DD + d0];
  float r[8];
#pragma unroll
  for (int j = 0; j < 8; ++j)
    r[j] = w0 * bf2f((unsigned short)a[j]) + w1 * bf2f((unsigned short)b[j])
         + g * bf2f((unsigned short)s[j]);
  float4 o0 = {r[0], r[1], r[2], r[3]};
  float4 o1 = {r[4], r[5], r[6], r[7]};
  float* op = out + (size_t)t * DD + d0;
  *(float4*)op = o0;
  *(float4*)(op + 4) = o1;
}

// ---------------------------------------------------------------------------
extern "C" void kernel_launch(void* const* d_in, const int* in_sizes, int n_in,
                              void* d_out, int out_size, void* d_ws, size_t ws_size,
                              hipStream_t stream) {
  const float* x    = (const float*)d_in[0];
  const float* wr   = (const float*)d_in[1];
  const float* wi0  = (const float*)d_in[2];
  const float* wi1  = (const float*)d_in[3];
  const float* wo   = (const float*)d_in[4];
  const float* swi0 = (const float*)d_in[5];
  const float* swi1 = (const float*)d_in[6];
  const float* swo  = (const float*)d_in[7];
  const float* wg   = (const float*)d_in[8];
  float* out = (float*)d_out;

  char* ws = (char*)d_ws;
  int*   cnt    = (int*)(ws + 0);
  int*   fillc  = (int*)(ws + 64);
  int*   offs   = (int*)(ws + 128);
  int*   topk_i = (int*)(ws + 1024);
  float* topk_w = (float*)(ws + 33792);
  int*   btok   = (int*)(ws + 66560);
  float* gate   = (float*)(ws + 132096);
  int*   slotOf = (int*)(ws + 148480);
  int*   cnt_part   = (int*)(ws + 262144);                 // 32 KB
  float* proxy_part = (float*)(ws + 294912);               // 32 KB
  unsigned short* xb    = (unsigned short*)(ws + 1048576);   // 16 MB; reused as Ys
  unsigned short* H     = (unsigned short*)(ws + 17825792);  // 8 MB
  unsigned short* Hs    = (unsigned short*)(ws + 26214400);  // 4 MB
  unsigned short* wi0T  = (unsigned short*)(ws + 30408704);  // 16 MB; reused as Yr (+wi1T)
  unsigned short* wi1T  = (unsigned short*)(ws + 47185920);  // 16 MB
  unsigned short* woT   = (unsigned short*)(ws + 63963136);  // 16 MB
  unsigned short* swi0T = (unsigned short*)(ws + 80740352);  // 2 MB
  unsigned short* swi1T = (unsigned short*)(ws + 82837504);  // 2 MB
  unsigned short* swoT  = (unsigned short*)(ws + 84934656);  // 2 MB
  unsigned short* Ys = xb;
  unsigned short* Yr = wi0T;

  hipMemsetAsync(ws, 0, 256, stream);

  prep_kernel<<<27 * 64 + TT / 4, 256, 0, stream>>>(
      wi0, wi1, wo, swi0, swi1, swo, wi0T, wi1T, woT, swi0T, swi1T, swoT,
      x, wr, wg, xb, topk_i, topk_w, gate, cnt_part, proxy_part);
  offsets_loss_kernel<<<1, 256, 0, stream>>>(
      cnt_part, proxy_part, cnt, offs, out + (size_t)TT * DD);
  fill_kernel<<<(TT * 2) / 256, 256, 0, stream>>>(topk_i, offs, fillc, btok, slotOf);

  gemm1_kernel<<<dim3(MM / 64, 32, EE + 1), 256, 0, stream>>>(
      xb, wi0T, wi1T, swi0T, swi1T, H, Hs, btok, cnt, offs);
  gemm2_kernel<<<dim3(DD / 128, 32, EE + 1), 256, 0, stream>>>(
      H, Hs, woT, swoT, Yr, Ys, cnt, offs);
  combine_kernel<<<TT, 256, 0, stream>>>(Yr, Ys, slotOf, topk_w, gate, out);
}